// Round 5
// baseline (417.349 us; speedup 1.0000x reference)
//
#include <hip/hip_runtime.h>
#include <hip/hip_bf16.h>

#define NCH 128      // n_agt == n_ctx
#define EB  32       // edges per block (edge kernel)
#define NB  32       // nodes per block (node kernels)

typedef __attribute__((ext_vector_type(8))) short bf16x8;
typedef __attribute__((ext_vector_type(4))) float f32x4;

__device__ inline unsigned short f2bf(float v) {
    __hip_bfloat16 h = __float2bfloat16(v);
    return __builtin_bit_cast(unsigned short, h);
}

// 8 consecutive f32 -> bf16x8 (fallback path when no bf16 node cache)
__device__ inline bf16x8 cvt8(const float* __restrict__ p) {
    bf16x8 r;
#pragma unroll
    for (int i = 0; i < 8; ++i) r[i] = (short)f2bf(p[i]);
    return r;
}

// A-fragment load from a node-feature tensor (bf16 cache or f32 source)
template<bool BF>
__device__ inline bf16x8 load_row8(const void* __restrict__ src, int node, int koff) {
    if constexpr (BF)
        return *(const bf16x8*)((const unsigned short*)src + (size_t)node * NCH + koff);
    else
        return cvt8((const float*)src + (size_t)node * NCH + koff);
}

// ---------------------------------------------------------------------------
// Weight conversion: Wd2 | Wq | Wc1 | Wc2 | Wa | Wl  (131072 bf16 = 256 KB)
// ---------------------------------------------------------------------------
__global__ __launch_bounds__(256) void convert_weights_kernel(
    const float* __restrict__ w_d2, const float* __restrict__ w_q,
    const float* __restrict__ w_c1, const float* __restrict__ w_c2,
    const float* __restrict__ w_a,  const float* __restrict__ w_l,
    unsigned short* __restrict__ out)
{
    int i = blockIdx.x * 256 + threadIdx.x;
    const float* src; int off;
    if      (i < 16384)  { src = w_d2; off = i; }
    else if (i < 32768)  { src = w_q;  off = i - 16384; }
    else if (i < 81920)  { src = w_c1; off = i - 32768; }
    else if (i < 98304)  { src = w_c2; off = i - 81920; }
    else if (i < 114688) { src = w_a;  off = i - 98304; }
    else if (i < 131072) { src = w_l;  off = i - 114688; }
    else return;
    out[i] = f2bf(src[off]);
}

// ---------------------------------------------------------------------------
// Node-feature conversion: agts, ctx -> bf16 caches (vectorized, grid-stride)
// ---------------------------------------------------------------------------
__global__ __launch_bounds__(256) void convert_nodes_kernel(
    const float* __restrict__ a, const float* __restrict__ c,
    unsigned short* __restrict__ abf, unsigned short* __restrict__ cbf, int nq)
{
    const int stride = gridDim.x * blockDim.x;
    for (int i = blockIdx.x * blockDim.x + threadIdx.x; i < 2 * nq; i += stride) {
        const bool isa = i < nq;
        const int j = isa ? i : i - nq;
        float4 v = (isa ? (const float4*)a : (const float4*)c)[j];
        ushort4 o = { f2bf(v.x), f2bf(v.y), f2bf(v.z), f2bf(v.w) };
        (isa ? (ushort4*)abf : (ushort4*)cbf)[j] = o;
    }
}

// ---------------------------------------------------------------------------
// K=128 GEMM step, A from swizzled bf16 LDS tile (32 rows), B = W rows (global bf16)
// ---------------------------------------------------------------------------
__device__ inline void gemm_k128_lds(const unsigned short* __restrict__ A,
                                     const unsigned short* __restrict__ W,
                                     int lane, int wave, f32x4 (&acc)[2][2])
{
#pragma unroll
    for (int k = 0; k < 4; ++k) {
        const int koff = k * 32 + (lane >> 4) * 8;
        bf16x8 a[2], b[2];
#pragma unroll
        for (int m = 0; m < 2; ++m) {
            int r = m * 16 + (lane & 15);
            int byte = (r * 256 + koff * 2) ^ ((r & 7) << 4);
            a[m] = *(const bf16x8*)((const char*)A + byte);
        }
#pragma unroll
        for (int n = 0; n < 2; ++n) {
            int wr = wave * 32 + n * 16 + (lane & 15);
            b[n] = *(const bf16x8*)(W + (size_t)wr * NCH + koff);
        }
#pragma unroll
        for (int m = 0; m < 2; ++m)
#pragma unroll
            for (int n = 0; n < 2; ++n)
                acc[m][n] = __builtin_amdgcn_mfma_f32_16x16x32_bf16(a[m], b[n], acc[m][n], 0, 0, 0);
    }
}

// K=128 GEMM step, A gathered directly from a node tensor (rows h0, h1 per lane)
template<bool BF>
__device__ inline void gemm_k128_gather(const void* __restrict__ src, int h0, int h1,
                                        const unsigned short* __restrict__ W,
                                        int lane, int wave, f32x4 (&acc)[2][2])
{
#pragma unroll
    for (int k = 0; k < 4; ++k) {
        const int koff = k * 32 + (lane >> 4) * 8;
        bf16x8 a[2], b[2];
        a[0] = load_row8<BF>(src, h0, koff);
        a[1] = load_row8<BF>(src, h1, koff);
#pragma unroll
        for (int n = 0; n < 2; ++n) {
            int wr = wave * 32 + n * 16 + (lane & 15);
            b[n] = *(const bf16x8*)(W + (size_t)wr * NCH + koff);
        }
#pragma unroll
        for (int m = 0; m < 2; ++m)
#pragma unroll
            for (int n = 0; n < 2; ++n)
                acc[m][n] = __builtin_amdgcn_mfma_f32_16x16x32_bf16(a[m], b[n], acc[m][n], 0, 0, 0);
    }
}

// ---------------------------------------------------------------------------
// Fragment-domain GroupNorm stats for a 32x128 tile held as C-fragments.
// Fills mu[m][j], rs[m][j] for this thread's fragment rows. Contains one
// barrier (which also orders prior LDS A-reads vs subsequent repacking).
// ---------------------------------------------------------------------------
__device__ inline void gn_frag_stats(const f32x4 (&acc)[2][2],
                                     float (*red_s)[4], float (*red_q)[4],
                                     int t, float (&mu)[2][4], float (&rs)[2][4])
{
    const int lane = t & 63, wave = t >> 6;
    float s[2][4], q[2][4];
#pragma unroll
    for (int m = 0; m < 2; ++m)
#pragma unroll
        for (int j = 0; j < 4; ++j) {
            float sv = acc[m][0][j] + acc[m][1][j];
            float qv = acc[m][0][j] * acc[m][0][j] + acc[m][1][j] * acc[m][1][j];
#pragma unroll
            for (int off = 1; off < 16; off <<= 1) {
                sv += __shfl_xor(sv, off);
                qv += __shfl_xor(qv, off);
            }
            s[m][j] = sv; q[m][j] = qv;
        }
    if ((lane & 15) == 0) {
        const int rg = lane >> 4;
#pragma unroll
        for (int m = 0; m < 2; ++m)
#pragma unroll
            for (int j = 0; j < 4; ++j) {
                int r = m * 16 + rg * 4 + j;
                red_s[r][wave] = s[m][j];
                red_q[r][wave] = q[m][j];
            }
    }
    __syncthreads();
#pragma unroll
    for (int m = 0; m < 2; ++m)
#pragma unroll
        for (int j = 0; j < 4; ++j) {
            int r = m * 16 + ((lane >> 4) << 2) + j;
            float4 sv = *(const float4*)red_s[r];
            float4 qv = *(const float4*)red_q[r];
            float ssum = (sv.x + sv.y) + (sv.z + sv.w);
            float qsum = (qv.x + qv.y) + (qv.z + qv.w);
            float m_  = ssum * (1.f / NCH);
            float var = qsum * (1.f / NCH) - m_ * m_;
            mu[m][j] = m_;
            rs[m][j] = rsqrtf(var + 1e-5f);
        }
}

// Apply GN + ReLU to fragments and pack bf16 into swizzled LDS tile dst.
__device__ inline void gn_pack_store(const f32x4 (&acc)[2][2],
                                     const float (&mu)[2][4], const float (&rs)[2][4],
                                     const float* __restrict__ gamma,
                                     const float* __restrict__ beta,
                                     unsigned short* __restrict__ dst, int t)
{
    const int lane = t & 63, wave = t >> 6;
    const int c0 = wave * 32 + (lane & 15);
    const float g0 = gamma[c0],      b0 = beta[c0];
    const float g1 = gamma[c0 + 16], b1 = beta[c0 + 16];
#pragma unroll
    for (int m = 0; m < 2; ++m)
#pragma unroll
        for (int j = 0; j < 4; ++j) {
            int r = m * 16 + ((lane >> 4) << 2) + j;
            float v0 = fmaxf((acc[m][0][j] - mu[m][j]) * rs[m][j] * g0 + b0, 0.f);
            float v1 = fmaxf((acc[m][1][j] - mu[m][j]) * rs[m][j] * g1 + b1, 0.f);
            unsigned int p0 = f2bf(v0), p1 = f2bf(v1);
            unsigned int o0 = (unsigned int)__shfl_xor((int)p0, 1);
            unsigned int o1 = (unsigned int)__shfl_xor((int)p1, 1);
            if (!(lane & 1)) {
                int cb = c0 * 2;
                int byte0 = (r * 256 + cb) ^ ((r & 7) << 4);
                int byte1 = (r * 256 + cb + 32) ^ ((r & 7) << 4);
                *(unsigned int*)((char*)dst + byte0) = (p0 & 0xffffu) | (o0 << 16);
                *(unsigned int*)((char*)dst + byte1) = (p1 & 0xffffu) | (o1 << 16);
            }
        }
    __syncthreads();
}

// ---------------------------------------------------------------------------
// Fused edge pipeline (MFMA): d1 -> d2(GN) ; q(GN) ; c1(GN, K=384) ; c2 -> scatter
// A-operands for q and ctx are gathered straight from node tensors (no staging).
// ---------------------------------------------------------------------------
template<bool BF>
__global__ __launch_bounds__(256) void edge_kernel(
    const void* __restrict__ agts_nb, const void* __restrict__ ctx_nb,
    const float* __restrict__ agt_ctrs, const float* __restrict__ ctx_ctrs,
    const int* __restrict__ hi, const int* __restrict__ wi,
    const float* __restrict__ w_d1, const float* __restrict__ b_d1,
    const float* __restrict__ g_d2, const float* __restrict__ bt_d2,
    const float* __restrict__ g_q, const float* __restrict__ bt_q,
    const float* __restrict__ g_c1, const float* __restrict__ bt_c1,
    const unsigned short* __restrict__ wbf,
    float* __restrict__ outbuf, int E)
{
    const int t = threadIdx.x;
    const int lane = t & 63;
    const int wave = t >> 6;
    const int e0 = blockIdx.x * EB;

    __shared__ unsigned short bfD[EB * NCH];   // d1 -> d2 -> c1 tile
    __shared__ unsigned short bfQ[EB * NCH];   // q tile
    __shared__ __align__(16) float red_s[EB][4];
    __shared__ __align__(16) float red_q[EB][4];
    __shared__ int   sh_h[EB], sh_w[EB];
    __shared__ float sh_dx[EB], sh_dy[EB];

    const unsigned short* Wd2 = wbf;
    const unsigned short* Wq  = wbf + 16384;
    const unsigned short* Wc1 = wbf + 32768;
    const unsigned short* Wc2 = wbf + 81920;

    if (t < EB) {
        int e = e0 + t; if (e >= E) e = E - 1;
        int h = hi[e], w = wi[e];
        sh_h[t] = h; sh_w[t] = w;
        sh_dx[t] = agt_ctrs[2 * h]     - ctx_ctrs[2 * w];
        sh_dy[t] = agt_ctrs[2 * h + 1] - ctx_ctrs[2 * w + 1];
    }
    __syncthreads();

    const int h0 = sh_h[lane & 15], h1 = sh_h[16 + (lane & 15)];
    const int w0 = sh_w[lane & 15], w1 = sh_w[16 + (lane & 15)];

    // d1 = relu(w_d1 . [dx,dy] + b_d1)   -> bfD (swizzled bf16)
    {
        const int c = t & 127, rh = t >> 7;
        const float wa = w_d1[2 * c], wb = w_d1[2 * c + 1], bb = b_d1[c];
#pragma unroll
        for (int i = 0; i < 16; ++i) {
            int r = rh * 16 + i;
            float v = fmaxf(fmaf(wa, sh_dx[r], fmaf(wb, sh_dy[r], bb)), 0.f);
            unsigned int pv = f2bf(v);
            unsigned int ov = (unsigned int)__shfl_xor((int)pv, 1);
            if (!(c & 1)) {
                int byte = (r * 256 + c * 2) ^ ((r & 7) << 4);
                *(unsigned int*)((char*)bfD + byte) = (pv & 0xffffu) | (ov << 16);
            }
        }
    }
    __syncthreads();

    const f32x4 z = { 0.f, 0.f, 0.f, 0.f };
    f32x4 acc[2][2];
    float mu[2][4], rs[2][4];

    // ---- d2 = relu(GN(d1 @ Wd2^T)) -> bfD ----
    acc[0][0] = z; acc[0][1] = z; acc[1][0] = z; acc[1][1] = z;
    gemm_k128_lds(bfD, Wd2, lane, wave, acc);
    gn_frag_stats(acc, red_s, red_q, t, mu, rs);
    gn_pack_store(acc, mu, rs, g_d2, bt_d2, bfD, t);

    // ---- q = relu(GN(agts[hi] @ Wq^T)) -> bfQ ----
    acc[0][0] = z; acc[0][1] = z; acc[1][0] = z; acc[1][1] = z;
    gemm_k128_gather<BF>(agts_nb, h0, h1, Wq, lane, wave, acc);
    gn_frag_stats(acc, red_s, red_q, t, mu, rs);
    gn_pack_store(acc, mu, rs, g_q, bt_q, bfQ, t);

    // ---- c1 = relu(GN([d2|q|ctx] @ Wc1^T)) -> bfD ----  (K = 384)
    acc[0][0] = z; acc[0][1] = z; acc[1][0] = z; acc[1][1] = z;
#pragma unroll
    for (int kt = 0; kt < 12; ++kt) {
        const int koff = (kt & 3) * 32 + (lane >> 4) * 8;
        bf16x8 a[2], b[2];
        if (kt < 8) {
            const unsigned short* Ab = (kt < 4) ? bfD : bfQ;
#pragma unroll
            for (int m = 0; m < 2; ++m) {
                int r = m * 16 + (lane & 15);
                int byte = (r * 256 + koff * 2) ^ ((r & 7) << 4);
                a[m] = *(const bf16x8*)((const char*)Ab + byte);
            }
        } else {
            const int ck = (kt - 8) * 32 + (lane >> 4) * 8;
            a[0] = load_row8<BF>(ctx_nb, w0, ck);
            a[1] = load_row8<BF>(ctx_nb, w1, ck);
        }
#pragma unroll
        for (int n = 0; n < 2; ++n) {
            int wr = wave * 32 + n * 16 + (lane & 15);
            b[n] = *(const bf16x8*)(Wc1 + (size_t)wr * 384 + kt * 32 + (lane >> 4) * 8);
        }
#pragma unroll
        for (int m = 0; m < 2; ++m)
#pragma unroll
            for (int n = 0; n < 2; ++n)
                acc[m][n] = __builtin_amdgcn_mfma_f32_16x16x32_bf16(a[m], b[n], acc[m][n], 0, 0, 0);
    }
    gn_frag_stats(acc, red_s, red_q, t, mu, rs);
    gn_pack_store(acc, mu, rs, g_c1, bt_c1, bfD, t);

    // ---- e = c1 @ Wc2^T ; scatter-add to outbuf[hi] ----
    acc[0][0] = z; acc[0][1] = z; acc[1][0] = z; acc[1][1] = z;
    gemm_k128_lds(bfD, Wc2, lane, wave, acc);
#pragma unroll
    for (int m = 0; m < 2; ++m)
#pragma unroll
        for (int n = 0; n < 2; ++n)
#pragma unroll
            for (int j = 0; j < 4; ++j) {
                int r = m * 16 + ((lane >> 4) << 2) + j;
                if (e0 + r < E)
                    atomicAdd(&outbuf[(size_t)sh_h[r] * NCH + wave * 32 + n * 16 + (lane & 15)],
                              acc[m][n][j]);
            }
}

// ---------------------------------------------------------------------------
// node_init: out = agts @ w_a^T via MFMA, 32 nodes/block, no LDS.
// ---------------------------------------------------------------------------
template<bool BF>
__global__ __launch_bounds__(256) void node_init_kernel(
    const void* __restrict__ agts_nb, const unsigned short* __restrict__ wa_bf,
    float* __restrict__ outbuf, int N)
{
    const int t = threadIdx.x;
    const int lane = t & 63, wave = t >> 6;
    const int n0 = blockIdx.x * NB;

    int r0 = n0 + (lane & 15);      if (r0 >= N) r0 = N - 1;
    int r1 = n0 + 16 + (lane & 15); if (r1 >= N) r1 = N - 1;

    const f32x4 z = { 0.f, 0.f, 0.f, 0.f };
    f32x4 acc[2][2] = { { z, z }, { z, z } };
#pragma unroll
    for (int k = 0; k < 4; ++k) {
        const int koff = k * 32 + (lane >> 4) * 8;
        bf16x8 a[2], b[2];
        a[0] = load_row8<BF>(agts_nb, r0, koff);
        a[1] = load_row8<BF>(agts_nb, r1, koff);
#pragma unroll
        for (int n = 0; n < 2; ++n) {
            int wr = wave * 32 + n * 16 + (lane & 15);
            b[n] = *(const bf16x8*)(wa_bf + (size_t)wr * NCH + koff);
        }
#pragma unroll
        for (int m = 0; m < 2; ++m)
#pragma unroll
            for (int n = 0; n < 2; ++n)
                acc[m][n] = __builtin_amdgcn_mfma_f32_16x16x32_bf16(a[m], b[n], acc[m][n], 0, 0, 0);
    }
#pragma unroll
    for (int m = 0; m < 2; ++m)
#pragma unroll
        for (int n = 0; n < 2; ++n)
#pragma unroll
            for (int j = 0; j < 4; ++j) {
                int r = m * 16 + ((lane >> 4) << 2) + j;
                int ng = n0 + r;
                if (ng < N)
                    outbuf[(size_t)ng * NCH + wave * 32 + n * 16 + (lane & 15)] = acc[m][n][j];
            }
}

// ---------------------------------------------------------------------------
// node_post: relu(GN(out)) -> GN(out @ w_l^T) -> relu(+ res), in place, MFMA.
// 32 nodes/block, 256 threads.
// ---------------------------------------------------------------------------
__global__ __launch_bounds__(256) void node_post_kernel(
    float* __restrict__ outbuf, const float* __restrict__ agts,
    const float* __restrict__ g_n, const float* __restrict__ bt_n,
    const unsigned short* __restrict__ wl_bf,
    const float* __restrict__ g_l, const float* __restrict__ bt_l, int N)
{
    const int t = threadIdx.x;
    const int lane = t & 63, wave = t >> 6;
    const int n0 = blockIdx.x * NB;

    __shared__ unsigned short bfP[NB * NCH];
    __shared__ __align__(16) float red_s[NB][4];
    __shared__ __align__(16) float red_q[NB][4];

    // ---- GN1 (channel-owner layout): thread owns channel c of rows rh*16..+15
    const int c = t & 127, rh = t >> 7;
    float v[16];
#pragma unroll
    for (int i = 0; i < 16; ++i) {
        int n = n0 + rh * 16 + i; if (n >= N) n = N - 1;
        v[i] = outbuf[(size_t)n * NCH + c];
    }
#pragma unroll
    for (int i = 0; i < 16; ++i) {
        float s = v[i], q = v[i] * v[i];
        for (int off = 32; off > 0; off >>= 1) {
            s += __shfl_down(s, off);
            q += __shfl_down(q, off);
        }
        if (lane == 0) { red_s[rh * 16 + i][wave & 1] = s; red_q[rh * 16 + i][wave & 1] = q; }
    }
    __syncthreads();
    {
        const float g = g_n[c], b = bt_n[c];
#pragma unroll
        for (int i = 0; i < 16; ++i) {
            int r = rh * 16 + i;
            float s = red_s[r][0] + red_s[r][1];
            float q = red_q[r][0] + red_q[r][1];
            float m_  = s * (1.f / NCH);
            float var = q * (1.f / NCH) - m_ * m_;
            float rrs = rsqrtf(var + 1e-5f);
            float val = fmaxf((v[i] - m_) * rrs * g + b, 0.f);
            unsigned int pv = f2bf(val);
            unsigned int ov = (unsigned int)__shfl_xor((int)pv, 1);
            if (!(c & 1)) {
                int byte = (r * 256 + c * 2) ^ ((r & 7) << 4);
                *(unsigned int*)((char*)bfP + byte) = (pv & 0xffffu) | (ov << 16);
            }
        }
    }
    __syncthreads();

    // ---- MFMA: h = gn1 @ w_l^T
    const f32x4 z = { 0.f, 0.f, 0.f, 0.f };
    f32x4 acc[2][2] = { { z, z }, { z, z } };
    gemm_k128_lds(bfP, wl_bf, lane, wave, acc);

    // ---- GN2 (no relu) + residual + relu, store in place
    float mu[2][4], rs[2][4];
    gn_frag_stats(acc, red_s, red_q, t, mu, rs);
    const int c0 = wave * 32 + (lane & 15);
    const float g0 = g_l[c0],      b0 = bt_l[c0];
    const float g1 = g_l[c0 + 16], b1 = bt_l[c0 + 16];
#pragma unroll
    for (int m = 0; m < 2; ++m)
#pragma unroll
        for (int j = 0; j < 4; ++j) {
            int r = m * 16 + ((lane >> 4) << 2) + j;
            int ng = n0 + r;
            if (ng < N) {
                float v0 = (acc[m][0][j] - mu[m][j]) * rs[m][j] * g0 + b0;
                float v1 = (acc[m][1][j] - mu[m][j]) * rs[m][j] * g1 + b1;
                v0 = fmaxf(v0 + agts[(size_t)ng * NCH + c0], 0.f);
                v1 = fmaxf(v1 + agts[(size_t)ng * NCH + c0 + 16], 0.f);
                outbuf[(size_t)ng * NCH + c0]      = v0;
                outbuf[(size_t)ng * NCH + c0 + 16] = v1;
            }
        }
}

// ---------------------------------------------------------------------------
extern "C" void kernel_launch(void* const* d_in, const int* in_sizes, int n_in,
                              void* d_out, int out_size, void* d_ws, size_t ws_size,
                              hipStream_t stream) {
    const float* agts     = (const float*)d_in[0];
    const float* ctx      = (const float*)d_in[1];
    const float* agt_ctrs = (const float*)d_in[2];
    const float* ctx_ctrs = (const float*)d_in[3];
    const int*   hi       = (const int*)d_in[4];
    const int*   wi       = (const int*)d_in[5];
    const float* w_d1     = (const float*)d_in[6];
    const float* b_d1     = (const float*)d_in[7];
    const float* w_d2     = (const float*)d_in[8];
    const float* g_d2     = (const float*)d_in[9];
    const float* bt_d2    = (const float*)d_in[10];
    const float* w_q      = (const float*)d_in[11];
    const float* g_q      = (const float*)d_in[12];
    const float* bt_q     = (const float*)d_in[13];
    const float* w_c1     = (const float*)d_in[14];
    const float* g_c1     = (const float*)d_in[15];
    const float* bt_c1    = (const float*)d_in[16];
    const float* w_c2     = (const float*)d_in[17];
    const float* w_a      = (const float*)d_in[18];
    const float* g_n      = (const float*)d_in[19];
    const float* bt_n     = (const float*)d_in[20];
    const float* w_l      = (const float*)d_in[21];
    const float* g_l      = (const float*)d_in[22];
    const float* bt_l     = (const float*)d_in[23];

    const int N = in_sizes[0] / NCH;
    const int E = in_sizes[4];

    float* outbuf = (float*)d_out;                 // [N,128] f32 accumulator

    unsigned short* wbf = (unsigned short*)d_ws;   // 131072 bf16 weights
    unsigned short* abf = wbf + 131072;            // agts bf16 cache
    unsigned short* cbf = abf + (size_t)N * NCH;   // ctx  bf16 cache
    const size_t need = 262144ull + (size_t)N * NCH * 4ull;  // bytes
    const bool big = (d_ws != nullptr) && (ws_size >= need);

    const int nb_nodes = (N + NB - 1) / NB;
    const int nb_edges = (E + EB - 1) / EB;

    convert_weights_kernel<<<512, 256, 0, stream>>>(w_d2, w_q, w_c1, w_c2, w_a, w_l, wbf);

    if (big) {
        convert_nodes_kernel<<<2048, 256, 0, stream>>>(agts, ctx, abf, cbf, N * NCH / 4);
        node_init_kernel<true><<<nb_nodes, 256, 0, stream>>>(abf, wbf + 98304, outbuf, N);
        edge_kernel<true><<<nb_edges, 256, 0, stream>>>(
            abf, cbf, agt_ctrs, ctx_ctrs, hi, wi,
            w_d1, b_d1, g_d2, bt_d2, g_q, bt_q, g_c1, bt_c1,
            wbf, outbuf, E);
    } else {
        node_init_kernel<false><<<nb_nodes, 256, 0, stream>>>(agts, wbf + 98304, outbuf, N);
        edge_kernel<false><<<nb_edges, 256, 0, stream>>>(
            agts, ctx, agt_ctrs, ctx_ctrs, hi, wi,
            w_d1, b_d1, g_d2, bt_d2, g_q, bt_q, g_c1, bt_c1,
            wbf, outbuf, E);
    }
    node_post_kernel<<<nb_nodes, 256, 0, stream>>>(
        outbuf, agts, g_n, bt_n, wbf + 114688, g_l, bt_l, N);
}

// Round 6
// 366.732 us; speedup vs baseline: 1.1380x; 1.1380x over previous
//
#include <hip/hip_runtime.h>
#include <hip/hip_bf16.h>

#define NCH 128      // n_agt == n_ctx
#define EB  32       // edges per block (edge kernel)
#define NB  32       // nodes per block (node kernels)

typedef __attribute__((ext_vector_type(8))) short bf16x8;
typedef __attribute__((ext_vector_type(4))) float f32x4;

__device__ inline unsigned short f2bf(float v) {
    __hip_bfloat16 h = __float2bfloat16(v);
    return __builtin_bit_cast(unsigned short, h);
}

// 8 consecutive f32 -> bf16x8 (fallback path when no bf16 node cache)
__device__ inline bf16x8 cvt8(const float* __restrict__ p) {
    bf16x8 r;
#pragma unroll
    for (int i = 0; i < 8; ++i) r[i] = (short)f2bf(p[i]);
    return r;
}

template<bool BF>
__device__ inline bf16x8 load_row8(const void* __restrict__ src, int node, int koff) {
    if constexpr (BF)
        return *(const bf16x8*)((const unsigned short*)src + (size_t)node * NCH + koff);
    else
        return cvt8((const float*)src + (size_t)node * NCH + koff);
}

// ---------------------------------------------------------------------------
// Weight conversion: Wd2 | Wq | Wc1 | Wc2 | Wa | Wl  (131072 bf16 = 256 KB)
// ---------------------------------------------------------------------------
__global__ __launch_bounds__(256) void convert_weights_kernel(
    const float* __restrict__ w_d2, const float* __restrict__ w_q,
    const float* __restrict__ w_c1, const float* __restrict__ w_c2,
    const float* __restrict__ w_a,  const float* __restrict__ w_l,
    unsigned short* __restrict__ out)
{
    int i = blockIdx.x * 256 + threadIdx.x;
    const float* src; int off;
    if      (i < 16384)  { src = w_d2; off = i; }
    else if (i < 32768)  { src = w_q;  off = i - 16384; }
    else if (i < 81920)  { src = w_c1; off = i - 32768; }
    else if (i < 98304)  { src = w_c2; off = i - 81920; }
    else if (i < 114688) { src = w_a;  off = i - 98304; }
    else if (i < 131072) { src = w_l;  off = i - 114688; }
    else return;
    out[i] = f2bf(src[off]);
}

// ---------------------------------------------------------------------------
// Node-feature conversion: agts, ctx -> bf16 caches (vectorized, grid-stride)
// ---------------------------------------------------------------------------
__global__ __launch_bounds__(256) void convert_nodes_kernel(
    const float* __restrict__ a, const float* __restrict__ c,
    unsigned short* __restrict__ abf, unsigned short* __restrict__ cbf, int nq)
{
    const int stride = gridDim.x * blockDim.x;
    for (int i = blockIdx.x * blockDim.x + threadIdx.x; i < 2 * nq; i += stride) {
        const bool isa = i < nq;
        const int j = isa ? i : i - nq;
        float4 v = (isa ? (const float4*)a : (const float4*)c)[j];
        ushort4 o = { f2bf(v.x), f2bf(v.y), f2bf(v.z), f2bf(v.w) };
        (isa ? (ushort4*)abf : (ushort4*)cbf)[j] = o;
    }
}

// ---------------------------------------------------------------------------
// K=128 GEMM step, A from swizzled bf16 LDS tile (32 rows), B = W rows (global bf16)
// ---------------------------------------------------------------------------
__device__ inline void gemm_k128_lds(const unsigned short* __restrict__ A,
                                     const unsigned short* __restrict__ W,
                                     int lane, int wave, f32x4 (&acc)[2][2])
{
#pragma unroll
    for (int k = 0; k < 4; ++k) {
        const int koff = k * 32 + (lane >> 4) * 8;
        bf16x8 a[2], b[2];
#pragma unroll
        for (int m = 0; m < 2; ++m) {
            int r = m * 16 + (lane & 15);
            int byte = (r * 256 + koff * 2) ^ ((r & 7) << 4);
            a[m] = *(const bf16x8*)((const char*)A + byte);
        }
#pragma unroll
        for (int n = 0; n < 2; ++n) {
            int wr = wave * 32 + n * 16 + (lane & 15);
            b[n] = *(const bf16x8*)(W + (size_t)wr * NCH + koff);
        }
#pragma unroll
        for (int m = 0; m < 2; ++m)
#pragma unroll
            for (int n = 0; n < 2; ++n)
                acc[m][n] = __builtin_amdgcn_mfma_f32_16x16x32_bf16(a[m], b[n], acc[m][n], 0, 0, 0);
    }
}

// ---------------------------------------------------------------------------
// Fragment-domain GroupNorm stats for a 32x128 tile held as C-fragments.
// One barrier; it also orders all waves' prior LDS reads before later packs.
// ---------------------------------------------------------------------------
__device__ inline void gn_frag_stats(const f32x4 (&acc)[2][2],
                                     float (*red_s)[4], float (*red_q)[4],
                                     int t, float (&mu)[2][4], float (&rs)[2][4])
{
    const int lane = t & 63, wave = t >> 6;
    float s[2][4], q[2][4];
#pragma unroll
    for (int m = 0; m < 2; ++m)
#pragma unroll
        for (int j = 0; j < 4; ++j) {
            float sv = acc[m][0][j] + acc[m][1][j];
            float qv = acc[m][0][j] * acc[m][0][j] + acc[m][1][j] * acc[m][1][j];
#pragma unroll
            for (int off = 1; off < 16; off <<= 1) {
                sv += __shfl_xor(sv, off);
                qv += __shfl_xor(qv, off);
            }
            s[m][j] = sv; q[m][j] = qv;
        }
    if ((lane & 15) == 0) {
        const int rg = lane >> 4;
#pragma unroll
        for (int m = 0; m < 2; ++m)
#pragma unroll
            for (int j = 0; j < 4; ++j) {
                int r = m * 16 + rg * 4 + j;
                red_s[r][wave] = s[m][j];
                red_q[r][wave] = q[m][j];
            }
    }
    __syncthreads();
#pragma unroll
    for (int m = 0; m < 2; ++m)
#pragma unroll
        for (int j = 0; j < 4; ++j) {
            int r = m * 16 + ((lane >> 4) << 2) + j;
            float4 sv = *(const float4*)red_s[r];
            float4 qv = *(const float4*)red_q[r];
            float ssum = (sv.x + sv.y) + (sv.z + sv.w);
            float qsum = (qv.x + qv.y) + (qv.z + qv.w);
            float m_  = ssum * (1.f / NCH);
            float var = qsum * (1.f / NCH) - m_ * m_;
            mu[m][j] = m_;
            rs[m][j] = rsqrtf(var + 1e-5f);
        }
}

// Apply GN + ReLU to fragments and pack bf16 into swizzled LDS tile dst.
// dst MAY be a tile that was read by the immediately-preceding GEMM: the
// barrier inside gn_frag_stats guarantees those reads completed.
__device__ inline void gn_pack_store(const f32x4 (&acc)[2][2],
                                     const float (&mu)[2][4], const float (&rs)[2][4],
                                     const float* __restrict__ gamma,
                                     const float* __restrict__ beta,
                                     unsigned short* __restrict__ dst, int t)
{
    const int lane = t & 63, wave = t >> 6;
    const int c0 = wave * 32 + (lane & 15);
    const float g0 = gamma[c0],      b0 = beta[c0];
    const float g1 = gamma[c0 + 16], b1 = beta[c0 + 16];
#pragma unroll
    for (int m = 0; m < 2; ++m)
#pragma unroll
        for (int j = 0; j < 4; ++j) {
            int r = m * 16 + ((lane >> 4) << 2) + j;
            float v0 = fmaxf((acc[m][0][j] - mu[m][j]) * rs[m][j] * g0 + b0, 0.f);
            float v1 = fmaxf((acc[m][1][j] - mu[m][j]) * rs[m][j] * g1 + b1, 0.f);
            unsigned int p0 = f2bf(v0), p1 = f2bf(v1);
            unsigned int o0 = (unsigned int)__shfl_xor((int)p0, 1);
            unsigned int o1 = (unsigned int)__shfl_xor((int)p1, 1);
            if (!(lane & 1)) {
                int cb = c0 * 2;
                int byte0 = (r * 256 + cb) ^ ((r & 7) << 4);
                int byte1 = (r * 256 + cb + 32) ^ ((r & 7) << 4);
                *(unsigned int*)((char*)dst + byte0) = (p0 & 0xffffu) | (o0 << 16);
                *(unsigned int*)((char*)dst + byte1) = (p1 & 0xffffu) | (o1 << 16);
            }
        }
    __syncthreads();
}

// ---------------------------------------------------------------------------
// Fused edge pipeline (MFMA), 3 LDS tiles:
//   bfA: agts[hi] -> q ; bfD: d1 -> d2 -> c1 ; bfX: ctx[wi]
// ---------------------------------------------------------------------------
template<bool BF>
__global__ __launch_bounds__(256) void edge_kernel(
    const void* __restrict__ agts_nb, const void* __restrict__ ctx_nb,
    const float* __restrict__ agt_ctrs, const float* __restrict__ ctx_ctrs,
    const int* __restrict__ hi, const int* __restrict__ wi,
    const float* __restrict__ w_d1, const float* __restrict__ b_d1,
    const float* __restrict__ g_d2, const float* __restrict__ bt_d2,
    const float* __restrict__ g_q, const float* __restrict__ bt_q,
    const float* __restrict__ g_c1, const float* __restrict__ bt_c1,
    const unsigned short* __restrict__ wbf,
    float* __restrict__ outbuf, int E)
{
    const int t = threadIdx.x;
    const int lane = t & 63;
    const int wave = t >> 6;
    const int e0 = blockIdx.x * EB;

    __shared__ unsigned short bfA[EB * NCH];
    __shared__ unsigned short bfD[EB * NCH];
    __shared__ unsigned short bfX[EB * NCH];
    __shared__ __align__(16) float red_s[EB][4];
    __shared__ __align__(16) float red_q[EB][4];
    __shared__ int   sh_h[EB], sh_w[EB];
    __shared__ float sh_dx[EB], sh_dy[EB];

    const unsigned short* Wd2 = wbf;
    const unsigned short* Wq  = wbf + 16384;
    const unsigned short* Wc1 = wbf + 32768;
    const unsigned short* Wc2 = wbf + 81920;

    if (t < EB) {
        int e = e0 + t; if (e >= E) e = E - 1;
        int h = hi[e], w = wi[e];
        sh_h[t] = h; sh_w[t] = w;
        sh_dx[t] = agt_ctrs[2 * h]     - ctx_ctrs[2 * w];
        sh_dy[t] = agt_ctrs[2 * h + 1] - ctx_ctrs[2 * w + 1];
    }
    __syncthreads();

    // ---- stage agts[hi] -> bfA, ctx[wi] -> bfX (coalesced 16B chunks) ----
    {
        const int r  = t >> 3;       // 0..31 (row)
        const int cc = t & 7;        // 2 chunks of 16B per thread
        const int h = sh_h[r], w = sh_w[r];
#pragma unroll
        for (int half = 0; half < 2; ++half) {
            int c = cc + half * 8;   // chunk 0..15
            bf16x8 av = load_row8<BF>(agts_nb, h, c * 8);
            bf16x8 xv = load_row8<BF>(ctx_nb,  w, c * 8);
            int byte = (r * 256 + c * 16) ^ ((r & 7) << 4);
            *(bf16x8*)((char*)bfA + byte) = av;
            *(bf16x8*)((char*)bfX + byte) = xv;
        }
    }
    // ---- d1 = relu(w_d1 . [dx,dy] + b_d1) -> bfD ----
    {
        const int c = t & 127, rh = t >> 7;
        const float wa = w_d1[2 * c], wb = w_d1[2 * c + 1], bb = b_d1[c];
#pragma unroll
        for (int i = 0; i < 16; ++i) {
            int r = rh * 16 + i;
            float v = fmaxf(fmaf(wa, sh_dx[r], fmaf(wb, sh_dy[r], bb)), 0.f);
            unsigned int pv = f2bf(v);
            unsigned int ov = (unsigned int)__shfl_xor((int)pv, 1);
            if (!(c & 1)) {
                int byte = (r * 256 + c * 2) ^ ((r & 7) << 4);
                *(unsigned int*)((char*)bfD + byte) = (pv & 0xffffu) | (ov << 16);
            }
        }
    }
    __syncthreads();

    const f32x4 z = { 0.f, 0.f, 0.f, 0.f };
    f32x4 acc[2][2];
    float mu[2][4], rs[2][4];

    // ---- d2 = relu(GN(d1 @ Wd2^T)) -> bfD ----
    acc[0][0] = z; acc[0][1] = z; acc[1][0] = z; acc[1][1] = z;
    gemm_k128_lds(bfD, Wd2, lane, wave, acc);
    gn_frag_stats(acc, red_s, red_q, t, mu, rs);
    gn_pack_store(acc, mu, rs, g_d2, bt_d2, bfD, t);

    // ---- q = relu(GN(agts[hi] @ Wq^T)) -> bfA (overwrites agts tile) ----
    acc[0][0] = z; acc[0][1] = z; acc[1][0] = z; acc[1][1] = z;
    gemm_k128_lds(bfA, Wq, lane, wave, acc);
    gn_frag_stats(acc, red_s, red_q, t, mu, rs);
    gn_pack_store(acc, mu, rs, g_q, bt_q, bfA, t);

    // ---- c1 = relu(GN([d2|q|ctx] @ Wc1^T)) -> bfD ----  (K = 384)
    acc[0][0] = z; acc[0][1] = z; acc[1][0] = z; acc[1][1] = z;
#pragma unroll
    for (int kt = 0; kt < 12; ++kt) {
        const unsigned short* Ab = (kt < 4) ? bfD : (kt < 8) ? bfA : bfX;
        const int koff = (kt & 3) * 32 + (lane >> 4) * 8;
        bf16x8 a[2], b[2];
#pragma unroll
        for (int m = 0; m < 2; ++m) {
            int r = m * 16 + (lane & 15);
            int byte = (r * 256 + koff * 2) ^ ((r & 7) << 4);
            a[m] = *(const bf16x8*)((const char*)Ab + byte);
        }
#pragma unroll
        for (int n = 0; n < 2; ++n) {
            int wr = wave * 32 + n * 16 + (lane & 15);
            b[n] = *(const bf16x8*)(Wc1 + (size_t)wr * 384 + kt * 32 + (lane >> 4) * 8);
        }
#pragma unroll
        for (int m = 0; m < 2; ++m)
#pragma unroll
            for (int n = 0; n < 2; ++n)
                acc[m][n] = __builtin_amdgcn_mfma_f32_16x16x32_bf16(a[m], b[n], acc[m][n], 0, 0, 0);
    }
    gn_frag_stats(acc, red_s, red_q, t, mu, rs);
    gn_pack_store(acc, mu, rs, g_c1, bt_c1, bfD, t);

    // ---- e = c1 @ Wc2^T ; scatter-add to outbuf[hi] ----
    acc[0][0] = z; acc[0][1] = z; acc[1][0] = z; acc[1][1] = z;
    gemm_k128_lds(bfD, Wc2, lane, wave, acc);
#pragma unroll
    for (int m = 0; m < 2; ++m)
#pragma unroll
        for (int n = 0; n < 2; ++n)
#pragma unroll
            for (int j = 0; j < 4; ++j) {
                int r = m * 16 + ((lane >> 4) << 2) + j;
                if (e0 + r < E)
                    atomicAdd(&outbuf[(size_t)sh_h[r] * NCH + wave * 32 + n * 16 + (lane & 15)],
                              acc[m][n][j]);
            }
}

// ---------------------------------------------------------------------------
// node_init: out = agts @ w_a^T via MFMA, 32 nodes/block, no LDS.
// ---------------------------------------------------------------------------
template<bool BF>
__global__ __launch_bounds__(256) void node_init_kernel(
    const void* __restrict__ agts_nb, const unsigned short* __restrict__ wa_bf,
    float* __restrict__ outbuf, int N)
{
    const int t = threadIdx.x;
    const int lane = t & 63, wave = t >> 6;
    const int n0 = blockIdx.x * NB;

    int r0 = n0 + (lane & 15);      if (r0 >= N) r0 = N - 1;
    int r1 = n0 + 16 + (lane & 15); if (r1 >= N) r1 = N - 1;

    const f32x4 z = { 0.f, 0.f, 0.f, 0.f };
    f32x4 acc[2][2] = { { z, z }, { z, z } };
#pragma unroll
    for (int k = 0; k < 4; ++k) {
        const int koff = k * 32 + (lane >> 4) * 8;
        bf16x8 a[2], b[2];
        a[0] = load_row8<BF>(agts_nb, r0, koff);
        a[1] = load_row8<BF>(agts_nb, r1, koff);
#pragma unroll
        for (int n = 0; n < 2; ++n) {
            int wr = wave * 32 + n * 16 + (lane & 15);
            b[n] = *(const bf16x8*)(wa_bf + (size_t)wr * NCH + koff);
        }
#pragma unroll
        for (int m = 0; m < 2; ++m)
#pragma unroll
            for (int n = 0; n < 2; ++n)
                acc[m][n] = __builtin_amdgcn_mfma_f32_16x16x32_bf16(a[m], b[n], acc[m][n], 0, 0, 0);
    }
#pragma unroll
    for (int m = 0; m < 2; ++m)
#pragma unroll
        for (int n = 0; n < 2; ++n)
#pragma unroll
            for (int j = 0; j < 4; ++j) {
                int r = m * 16 + ((lane >> 4) << 2) + j;
                int ng = n0 + r;
                if (ng < N)
                    outbuf[(size_t)ng * NCH + wave * 32 + n * 16 + (lane & 15)] = acc[m][n][j];
            }
}

// ---------------------------------------------------------------------------
// node_post: relu(GN(out)) -> GN(out @ w_l^T) -> relu(+ res), in place, MFMA.
// ---------------------------------------------------------------------------
__global__ __launch_bounds__(256) void node_post_kernel(
    float* __restrict__ outbuf, const float* __restrict__ agts,
    const float* __restrict__ g_n, const float* __restrict__ bt_n,
    const unsigned short* __restrict__ wl_bf,
    const float* __restrict__ g_l, const float* __restrict__ bt_l, int N)
{
    const int t = threadIdx.x;
    const int lane = t & 63, wave = t >> 6;
    const int n0 = blockIdx.x * NB;

    __shared__ unsigned short bfP[NB * NCH];
    __shared__ __align__(16) float red_s[NB][4];
    __shared__ __align__(16) float red_q[NB][4];

    // ---- GN1 (channel-owner layout)
    const int c = t & 127, rh = t >> 7;
    float v[16];
#pragma unroll
    for (int i = 0; i < 16; ++i) {
        int n = n0 + rh * 16 + i; if (n >= N) n = N - 1;
        v[i] = outbuf[(size_t)n * NCH + c];
    }
#pragma unroll
    for (int i = 0; i < 16; ++i) {
        float s = v[i], q = v[i] * v[i];
        for (int off = 32; off > 0; off >>= 1) {
            s += __shfl_down(s, off);
            q += __shfl_down(q, off);
        }
        if (lane == 0) { red_s[rh * 16 + i][wave & 1] = s; red_q[rh * 16 + i][wave & 1] = q; }
    }
    __syncthreads();
    {
        const float g = g_n[c], b = bt_n[c];
#pragma unroll
        for (int i = 0; i < 16; ++i) {
            int r = rh * 16 + i;
            float s = red_s[r][0] + red_s[r][1];
            float q = red_q[r][0] + red_q[r][1];
            float m_  = s * (1.f / NCH);
            float var = q * (1.f / NCH) - m_ * m_;
            float rrs = rsqrtf(var + 1e-5f);
            float val = fmaxf((v[i] - m_) * rrs * g + b, 0.f);
            unsigned int pv = f2bf(val);
            unsigned int ov = (unsigned int)__shfl_xor((int)pv, 1);
            if (!(c & 1)) {
                int byte = (r * 256 + c * 2) ^ ((r & 7) << 4);
                *(unsigned int*)((char*)bfP + byte) = (pv & 0xffffu) | (ov << 16);
            }
        }
    }
    __syncthreads();

    // ---- MFMA: h = gn1 @ w_l^T
    const f32x4 z = { 0.f, 0.f, 0.f, 0.f };
    f32x4 acc[2][2] = { { z, z }, { z, z } };
    gemm_k128_lds(bfP, wl_bf, lane, wave, acc);

    // ---- GN2 (no relu) + residual + relu, store in place
    float mu[2][4], rs[2][4];
    gn_frag_stats(acc, red_s, red_q, t, mu, rs);
    const int c0 = wave * 32 + (lane & 15);
    const float g0 = g_l[c0],      b0 = bt_l[c0];
    const float g1 = g_l[c0 + 16], b1 = bt_l[c0 + 16];
#pragma unroll
    for (int m = 0; m < 2; ++m)
#pragma unroll
        for (int j = 0; j < 4; ++j) {
            int r = m * 16 + ((lane >> 4) << 2) + j;
            int ng = n0 + r;
            if (ng < N) {
                float v0 = (acc[m][0][j] - mu[m][j]) * rs[m][j] * g0 + b0;
                float v1 = (acc[m][1][j] - mu[m][j]) * rs[m][j] * g1 + b1;
                v0 = fmaxf(v0 + agts[(size_t)ng * NCH + c0], 0.f);
                v1 = fmaxf(v1 + agts[(size_t)ng * NCH + c0 + 16], 0.f);
                outbuf[(size_t)ng * NCH + c0]      = v0;
                outbuf[(size_t)ng * NCH + c0 + 16] = v1;
            }
        }
}

// ---------------------------------------------------------------------------
extern "C" void kernel_launch(void* const* d_in, const int* in_sizes, int n_in,
                              void* d_out, int out_size, void* d_ws, size_t ws_size,
                              hipStream_t stream) {
    const float* agts     = (const float*)d_in[0];
    const float* ctx      = (const float*)d_in[1];
    const float* agt_ctrs = (const float*)d_in[2];
    const float* ctx_ctrs = (const float*)d_in[3];
    const int*   hi       = (const int*)d_in[4];
    const int*   wi       = (const int*)d_in[5];
    const float* w_d1     = (const float*)d_in[6];
    const float* b_d1     = (const float*)d_in[7];
    const float* w_d2     = (const float*)d_in[8];
    const float* g_d2     = (const float*)d_in[9];
    const float* bt_d2    = (const float*)d_in[10];
    const float* w_q      = (const float*)d_in[11];
    const float* g_q      = (const float*)d_in[12];
    const float* bt_q     = (const float*)d_in[13];
    const float* w_c1     = (const float*)d_in[14];
    const float* g_c1     = (const float*)d_in[15];
    const float* bt_c1    = (const float*)d_in[16];
    const float* w_c2     = (const float*)d_in[17];
    const float* w_a      = (const float*)d_in[18];
    const float* g_n      = (const float*)d_in[19];
    const float* bt_n     = (const float*)d_in[20];
    const float* w_l      = (const float*)d_in[21];
    const float* g_l      = (const float*)d_in[22];
    const float* bt_l     = (const float*)d_in[23];

    const int N = in_sizes[0] / NCH;
    const int E = in_sizes[4];

    float* outbuf = (float*)d_out;                 // [N,128] f32 accumulator

    unsigned short* wbf = (unsigned short*)d_ws;   // 131072 bf16 weights
    unsigned short* abf = wbf + 131072;            // agts bf16 cache
    unsigned short* cbf = abf + (size_t)N * NCH;   // ctx  bf16 cache
    const size_t need = 262144ull + (size_t)N * NCH * 4ull;  // bytes
    const bool big = (d_ws != nullptr) && (ws_size >= need);

    const int nb_nodes = (N + NB - 1) / NB;
    const int nb_edges = (E + EB - 1) / EB;

    convert_weights_kernel<<<512, 256, 0, stream>>>(w_d2, w_q, w_c1, w_c2, w_a, w_l, wbf);

    if (big) {
        convert_nodes_kernel<<<2048, 256, 0, stream>>>(agts, ctx, abf, cbf, N * NCH / 4);
        node_init_kernel<true><<<nb_nodes, 256, 0, stream>>>(abf, wbf + 98304, outbuf, N);
        edge_kernel<true><<<nb_edges, 256, 0, stream>>>(
            abf, cbf, agt_ctrs, ctx_ctrs, hi, wi,
            w_d1, b_d1, g_d2, bt_d2, g_q, bt_q, g_c1, bt_c1,
            wbf, outbuf, E);
    } else {
        node_init_kernel<false><<<nb_nodes, 256, 0, stream>>>(agts, wbf + 98304, outbuf, N);
        edge_kernel<false><<<nb_edges, 256, 0, stream>>>(
            agts, ctx, agt_ctrs, ctx_ctrs, hi, wi,
            w_d1, b_d1, g_d2, bt_d2, g_q, bt_q, g_c1, bt_c1,
            wbf, outbuf, E);
    }
    node_post_kernel<<<nb_nodes, 256, 0, stream>>>(
        outbuf, agts, g_n, bt_n, wbf + 114688, g_l, bt_l, N);
}

// Round 7
// 325.679 us; speedup vs baseline: 1.2815x; 1.1261x over previous
//
#include <hip/hip_runtime.h>
#include <hip/hip_bf16.h>

#define NCH 128      // n_agt == n_ctx
#define EB  32       // edges per block (edge kernel)
#define NB  32       // nodes per block (node kernels)

typedef __attribute__((ext_vector_type(8))) short bf16x8;
typedef __attribute__((ext_vector_type(4))) float f32x4;

__device__ inline unsigned short f2bf(float v) {
    __hip_bfloat16 h = __float2bfloat16(v);
    return __builtin_bit_cast(unsigned short, h);
}

__device__ inline bf16x8 cvt8(const float* __restrict__ p) {
    bf16x8 r;
#pragma unroll
    for (int i = 0; i < 8; ++i) r[i] = (short)f2bf(p[i]);
    return r;
}

template<bool BF>
__device__ inline bf16x8 load_row8(const void* __restrict__ src, int node, int koff) {
    if constexpr (BF)
        return *(const bf16x8*)((const unsigned short*)src + (size_t)node * NCH + koff);
    else
        return cvt8((const float*)src + (size_t)node * NCH + koff);
}

// ---------------------------------------------------------------------------
// Weight conversion: Wd2 | Wq | Wc1 | Wc2 | Wa | Wl  (131072 bf16 = 256 KB)
// ---------------------------------------------------------------------------
__global__ __launch_bounds__(256) void convert_weights_kernel(
    const float* __restrict__ w_d2, const float* __restrict__ w_q,
    const float* __restrict__ w_c1, const float* __restrict__ w_c2,
    const float* __restrict__ w_a,  const float* __restrict__ w_l,
    unsigned short* __restrict__ out)
{
    int i = blockIdx.x * 256 + threadIdx.x;
    const float* src; int off;
    if      (i < 16384)  { src = w_d2; off = i; }
    else if (i < 32768)  { src = w_q;  off = i - 16384; }
    else if (i < 81920)  { src = w_c1; off = i - 32768; }
    else if (i < 98304)  { src = w_c2; off = i - 81920; }
    else if (i < 114688) { src = w_a;  off = i - 98304; }
    else if (i < 131072) { src = w_l;  off = i - 114688; }
    else return;
    out[i] = f2bf(src[off]);
}

// ---------------------------------------------------------------------------
// ctx -> bf16 cache (vectorized, grid-stride)
// ---------------------------------------------------------------------------
__global__ __launch_bounds__(256) void convert_ctx_kernel(
    const float* __restrict__ c, unsigned short* __restrict__ cbf, int nq)
{
    const int stride = gridDim.x * blockDim.x;
    for (int i = blockIdx.x * blockDim.x + threadIdx.x; i < nq; i += stride) {
        float4 v = ((const float4*)c)[i];
        ushort4 o = { f2bf(v.x), f2bf(v.y), f2bf(v.z), f2bf(v.w) };
        ((ushort4*)cbf)[i] = o;
    }
}

// ---------------------------------------------------------------------------
// K=128 GEMM step, A from swizzled bf16 LDS tile (32 rows), B = W rows (global bf16)
// ---------------------------------------------------------------------------
__device__ inline void gemm_k128_lds(const unsigned short* __restrict__ A,
                                     const unsigned short* __restrict__ W,
                                     int lane, int wave, f32x4 (&acc)[2][2])
{
#pragma unroll
    for (int k = 0; k < 4; ++k) {
        const int koff = k * 32 + (lane >> 4) * 8;
        bf16x8 a[2], b[2];
#pragma unroll
        for (int m = 0; m < 2; ++m) {
            int r = m * 16 + (lane & 15);
            int byte = (r * 256 + koff * 2) ^ ((r & 7) << 4);
            a[m] = *(const bf16x8*)((const char*)A + byte);
        }
#pragma unroll
        for (int n = 0; n < 2; ++n) {
            int wr = wave * 32 + n * 16 + (lane & 15);
            b[n] = *(const bf16x8*)(W + (size_t)wr * NCH + koff);
        }
#pragma unroll
        for (int m = 0; m < 2; ++m)
#pragma unroll
            for (int n = 0; n < 2; ++n)
                acc[m][n] = __builtin_amdgcn_mfma_f32_16x16x32_bf16(a[m], b[n], acc[m][n], 0, 0, 0);
    }
}

// ---------------------------------------------------------------------------
// Fragment-domain GroupNorm stats for a 32x128 tile held as C-fragments.
// One barrier; it also orders all waves' prior LDS reads before later packs.
// ---------------------------------------------------------------------------
__device__ inline void gn_frag_stats(const f32x4 (&acc)[2][2],
                                     float (*red_s)[4], float (*red_q)[4],
                                     int t, float (&mu)[2][4], float (&rs)[2][4])
{
    const int lane = t & 63, wave = t >> 6;
    float s[2][4], q[2][4];
#pragma unroll
    for (int m = 0; m < 2; ++m)
#pragma unroll
        for (int j = 0; j < 4; ++j) {
            float sv = acc[m][0][j] + acc[m][1][j];
            float qv = acc[m][0][j] * acc[m][0][j] + acc[m][1][j] * acc[m][1][j];
#pragma unroll
            for (int off = 1; off < 16; off <<= 1) {
                sv += __shfl_xor(sv, off);
                qv += __shfl_xor(qv, off);
            }
            s[m][j] = sv; q[m][j] = qv;
        }
    if ((lane & 15) == 0) {
        const int rg = lane >> 4;
#pragma unroll
        for (int m = 0; m < 2; ++m)
#pragma unroll
            for (int j = 0; j < 4; ++j) {
                int r = m * 16 + rg * 4 + j;
                red_s[r][wave] = s[m][j];
                red_q[r][wave] = q[m][j];
            }
    }
    __syncthreads();
#pragma unroll
    for (int m = 0; m < 2; ++m)
#pragma unroll
        for (int j = 0; j < 4; ++j) {
            int r = m * 16 + ((lane >> 4) << 2) + j;
            float4 sv = *(const float4*)red_s[r];
            float4 qv = *(const float4*)red_q[r];
            float ssum = (sv.x + sv.y) + (sv.z + sv.w);
            float qsum = (qv.x + qv.y) + (qv.z + qv.w);
            float m_  = ssum * (1.f / NCH);
            float var = qsum * (1.f / NCH) - m_ * m_;
            mu[m][j] = m_;
            rs[m][j] = rsqrtf(var + 1e-5f);
        }
}

// Apply GN + ReLU to fragments and pack bf16 into swizzled LDS tile dst.
__device__ inline void gn_pack_store(const f32x4 (&acc)[2][2],
                                     const float (&mu)[2][4], const float (&rs)[2][4],
                                     const float* __restrict__ gamma,
                                     const float* __restrict__ beta,
                                     unsigned short* __restrict__ dst, int t)
{
    const int lane = t & 63, wave = t >> 6;
    const int c0 = wave * 32 + (lane & 15);
    const float g0 = gamma[c0],      b0 = beta[c0];
    const float g1 = gamma[c0 + 16], b1 = beta[c0 + 16];
#pragma unroll
    for (int m = 0; m < 2; ++m)
#pragma unroll
        for (int j = 0; j < 4; ++j) {
            int r = m * 16 + ((lane >> 4) << 2) + j;
            float v0 = fmaxf((acc[m][0][j] - mu[m][j]) * rs[m][j] * g0 + b0, 0.f);
            float v1 = fmaxf((acc[m][1][j] - mu[m][j]) * rs[m][j] * g1 + b1, 0.f);
            unsigned int p0 = f2bf(v0), p1 = f2bf(v1);
            unsigned int o0 = (unsigned int)__shfl_xor((int)p0, 1);
            unsigned int o1 = (unsigned int)__shfl_xor((int)p1, 1);
            if (!(lane & 1)) {
                int cb = c0 * 2;
                int byte0 = (r * 256 + cb) ^ ((r & 7) << 4);
                int byte1 = (r * 256 + cb + 32) ^ ((r & 7) << 4);
                *(unsigned int*)((char*)dst + byte0) = (p0 & 0xffffu) | (o0 << 16);
                *(unsigned int*)((char*)dst + byte1) = (p1 & 0xffffu) | (o1 << 16);
            }
        }
    __syncthreads();
}

// ---------------------------------------------------------------------------
// node_prep: out = agts @ Wa^T (f32)  AND  qbf = relu(GN(agts @ Wq^T)) (bf16),
// sharing the A-fragment loads. 32 nodes/block, reads f32 agts directly.
// ---------------------------------------------------------------------------
__global__ __launch_bounds__(256) void node_prep_kernel(
    const float* __restrict__ agts,
    const unsigned short* __restrict__ wa_bf, const unsigned short* __restrict__ wq_bf,
    const float* __restrict__ g_q, const float* __restrict__ bt_q,
    float* __restrict__ outbuf, unsigned short* __restrict__ qbf, int N)
{
    const int t = threadIdx.x;
    const int lane = t & 63, wave = t >> 6;
    const int n0 = blockIdx.x * NB;

    __shared__ __align__(16) float red_s[NB][4];
    __shared__ __align__(16) float red_q[NB][4];

    int r0 = n0 + (lane & 15);      if (r0 >= N) r0 = N - 1;
    int r1 = n0 + 16 + (lane & 15); if (r1 >= N) r1 = N - 1;

    const f32x4 z = { 0.f, 0.f, 0.f, 0.f };
    f32x4 accO[2][2] = { { z, z }, { z, z } };
    f32x4 accQ[2][2] = { { z, z }, { z, z } };
#pragma unroll
    for (int k = 0; k < 4; ++k) {
        const int koff = k * 32 + (lane >> 4) * 8;
        bf16x8 a[2], bo[2], bq[2];
        a[0] = load_row8<false>(agts, r0, koff);
        a[1] = load_row8<false>(agts, r1, koff);
#pragma unroll
        for (int n = 0; n < 2; ++n) {
            int wr = wave * 32 + n * 16 + (lane & 15);
            bo[n] = *(const bf16x8*)(wa_bf + (size_t)wr * NCH + koff);
            bq[n] = *(const bf16x8*)(wq_bf + (size_t)wr * NCH + koff);
        }
#pragma unroll
        for (int m = 0; m < 2; ++m)
#pragma unroll
            for (int n = 0; n < 2; ++n) {
                accO[m][n] = __builtin_amdgcn_mfma_f32_16x16x32_bf16(a[m], bo[n], accO[m][n], 0, 0, 0);
                accQ[m][n] = __builtin_amdgcn_mfma_f32_16x16x32_bf16(a[m], bq[n], accQ[m][n], 0, 0, 0);
            }
    }
    // f32 store of the Wa product
#pragma unroll
    for (int m = 0; m < 2; ++m)
#pragma unroll
        for (int n = 0; n < 2; ++n)
#pragma unroll
            for (int j = 0; j < 4; ++j) {
                int r = m * 16 + ((lane >> 4) << 2) + j;
                int ng = n0 + r;
                if (ng < N)
                    outbuf[(size_t)ng * NCH + wave * 32 + n * 16 + (lane & 15)] = accO[m][n][j];
            }
    // GN + relu + bf16 pack of the Wq product -> global qbf (row-major)
    float mu[2][4], rs[2][4];
    gn_frag_stats(accQ, red_s, red_q, t, mu, rs);
    const int c0 = wave * 32 + (lane & 15);
    const float g0 = g_q[c0],      b0 = bt_q[c0];
    const float g1 = g_q[c0 + 16], b1 = bt_q[c0 + 16];
#pragma unroll
    for (int m = 0; m < 2; ++m)
#pragma unroll
        for (int j = 0; j < 4; ++j) {
            int r = m * 16 + ((lane >> 4) << 2) + j;
            int ng = n0 + r;
            float v0 = fmaxf((accQ[m][0][j] - mu[m][j]) * rs[m][j] * g0 + b0, 0.f);
            float v1 = fmaxf((accQ[m][1][j] - mu[m][j]) * rs[m][j] * g1 + b1, 0.f);
            unsigned int p0 = f2bf(v0), p1 = f2bf(v1);
            unsigned int o0 = (unsigned int)__shfl_xor((int)p0, 1);
            unsigned int o1 = (unsigned int)__shfl_xor((int)p1, 1);
            if (!(lane & 1) && ng < N) {
                unsigned int* rowp = (unsigned int*)((char*)qbf + (size_t)ng * 256);
                rowp[c0 >> 1]        = (p0 & 0xffffu) | (o0 << 16);
                rowp[(c0 + 16) >> 1] = (p1 & 0xffffu) | (o1 << 16);
            }
        }
}

// ---------------------------------------------------------------------------
// Fused edge pipeline (MFMA), 3 LDS tiles.
// BIG: bfQ stages precomputed q rows (bf16), bfX stages ctx (bf16).
// !BIG: bfQ stages agts rows (f32 src) and the q phase runs in-kernel.
// ---------------------------------------------------------------------------
template<bool BIG>
__global__ __launch_bounds__(256) void edge_kernel(
    const void* __restrict__ qsrc, const void* __restrict__ ctx_nb,
    const float* __restrict__ agt_ctrs, const float* __restrict__ ctx_ctrs,
    const int* __restrict__ hi, const int* __restrict__ wi,
    const float* __restrict__ w_d1, const float* __restrict__ b_d1,
    const float* __restrict__ g_d2, const float* __restrict__ bt_d2,
    const float* __restrict__ g_q, const float* __restrict__ bt_q,
    const float* __restrict__ g_c1, const float* __restrict__ bt_c1,
    const unsigned short* __restrict__ wbf,
    float* __restrict__ outbuf, int E)
{
    const int t = threadIdx.x;
    const int lane = t & 63;
    const int wave = t >> 6;
    const int e0 = blockIdx.x * EB;

    __shared__ unsigned short bfQ[EB * NCH];
    __shared__ unsigned short bfD[EB * NCH];
    __shared__ unsigned short bfX[EB * NCH];
    __shared__ __align__(16) float red_s[EB][4];
    __shared__ __align__(16) float red_q[EB][4];
    __shared__ int   sh_h[EB], sh_w[EB];
    __shared__ float sh_dx[EB], sh_dy[EB];

    const unsigned short* Wd2 = wbf;
    const unsigned short* Wq  = wbf + 16384;
    const unsigned short* Wc1 = wbf + 32768;
    const unsigned short* Wc2 = wbf + 81920;

    if (t < EB) {
        int e = e0 + t; if (e >= E) e = E - 1;
        int h = hi[e], w = wi[e];
        sh_h[t] = h; sh_w[t] = w;
        sh_dx[t] = agt_ctrs[2 * h]     - ctx_ctrs[2 * w];
        sh_dy[t] = agt_ctrs[2 * h + 1] - ctx_ctrs[2 * w + 1];
    }
    __syncthreads();

    // ---- stage q/agts -> bfQ, ctx -> bfX (coalesced 16B chunks) ----
    {
        const int r  = t >> 3;
        const int cc = t & 7;
        const int h = sh_h[r], w = sh_w[r];
#pragma unroll
        for (int half = 0; half < 2; ++half) {
            int c = cc + half * 8;
            bf16x8 qv = load_row8<BIG>(qsrc, h, c * 8);
            bf16x8 xv = load_row8<BIG>(ctx_nb, w, c * 8);
            int byte = (r * 256 + c * 16) ^ ((r & 7) << 4);
            *(bf16x8*)((char*)bfQ + byte) = qv;
            *(bf16x8*)((char*)bfX + byte) = xv;
        }
    }
    // ---- d1 = relu(w_d1 . [dx,dy] + b_d1) -> bfD ----
    {
        const int c = t & 127, rh = t >> 7;
        const float wa = w_d1[2 * c], wb = w_d1[2 * c + 1], bb = b_d1[c];
#pragma unroll
        for (int i = 0; i < 16; ++i) {
            int r = rh * 16 + i;
            float v = fmaxf(fmaf(wa, sh_dx[r], fmaf(wb, sh_dy[r], bb)), 0.f);
            unsigned int pv = f2bf(v);
            unsigned int ov = (unsigned int)__shfl_xor((int)pv, 1);
            if (!(c & 1)) {
                int byte = (r * 256 + c * 2) ^ ((r & 7) << 4);
                *(unsigned int*)((char*)bfD + byte) = (pv & 0xffffu) | (ov << 16);
            }
        }
    }
    __syncthreads();

    const f32x4 z = { 0.f, 0.f, 0.f, 0.f };
    f32x4 acc[2][2];
    float mu[2][4], rs[2][4];

    // ---- d2 = relu(GN(d1 @ Wd2^T)) -> bfD ----
    acc[0][0] = z; acc[0][1] = z; acc[1][0] = z; acc[1][1] = z;
    gemm_k128_lds(bfD, Wd2, lane, wave, acc);
    gn_frag_stats(acc, red_s, red_q, t, mu, rs);
    gn_pack_store(acc, mu, rs, g_d2, bt_d2, bfD, t);

    if constexpr (!BIG) {
        // ---- q = relu(GN(agts[hi] @ Wq^T)) -> bfQ ----
        acc[0][0] = z; acc[0][1] = z; acc[1][0] = z; acc[1][1] = z;
        gemm_k128_lds(bfQ, Wq, lane, wave, acc);
        gn_frag_stats(acc, red_s, red_q, t, mu, rs);
        gn_pack_store(acc, mu, rs, g_q, bt_q, bfQ, t);
    }

    // ---- c1 = relu(GN([d2|q|ctx] @ Wc1^T)) -> bfD ----  (K = 384)
    acc[0][0] = z; acc[0][1] = z; acc[1][0] = z; acc[1][1] = z;
#pragma unroll
    for (int kt = 0; kt < 12; ++kt) {
        const unsigned short* Ab = (kt < 4) ? bfD : (kt < 8) ? bfQ : bfX;
        const int koff = (kt & 3) * 32 + (lane >> 4) * 8;
        bf16x8 a[2], b[2];
#pragma unroll
        for (int m = 0; m < 2; ++m) {
            int r = m * 16 + (lane & 15);
            int byte = (r * 256 + koff * 2) ^ ((r & 7) << 4);
            a[m] = *(const bf16x8*)((const char*)Ab + byte);
        }
#pragma unroll
        for (int n = 0; n < 2; ++n) {
            int wr = wave * 32 + n * 16 + (lane & 15);
            b[n] = *(const bf16x8*)(Wc1 + (size_t)wr * 384 + kt * 32 + (lane >> 4) * 8);
        }
#pragma unroll
        for (int m = 0; m < 2; ++m)
#pragma unroll
            for (int n = 0; n < 2; ++n)
                acc[m][n] = __builtin_amdgcn_mfma_f32_16x16x32_bf16(a[m], b[n], acc[m][n], 0, 0, 0);
    }
    gn_frag_stats(acc, red_s, red_q, t, mu, rs);
    gn_pack_store(acc, mu, rs, g_c1, bt_c1, bfD, t);

    // ---- e = c1 @ Wc2^T ; scatter-add to outbuf[hi] ----
    acc[0][0] = z; acc[0][1] = z; acc[1][0] = z; acc[1][1] = z;
    gemm_k128_lds(bfD, Wc2, lane, wave, acc);
#pragma unroll
    for (int m = 0; m < 2; ++m)
#pragma unroll
        for (int n = 0; n < 2; ++n)
#pragma unroll
            for (int j = 0; j < 4; ++j) {
                int r = m * 16 + ((lane >> 4) << 2) + j;
                if (e0 + r < E)
                    atomicAdd(&outbuf[(size_t)sh_h[r] * NCH + wave * 32 + n * 16 + (lane & 15)],
                              acc[m][n][j]);
            }
}

// ---------------------------------------------------------------------------
// node_init (fallback only): out = agts @ w_a^T via MFMA.
// ---------------------------------------------------------------------------
__global__ __launch_bounds__(256) void node_init_kernel(
    const float* __restrict__ agts, const unsigned short* __restrict__ wa_bf,
    float* __restrict__ outbuf, int N)
{
    const int t = threadIdx.x;
    const int lane = t & 63, wave = t >> 6;
    const int n0 = blockIdx.x * NB;

    int r0 = n0 + (lane & 15);      if (r0 >= N) r0 = N - 1;
    int r1 = n0 + 16 + (lane & 15); if (r1 >= N) r1 = N - 1;

    const f32x4 z = { 0.f, 0.f, 0.f, 0.f };
    f32x4 acc[2][2] = { { z, z }, { z, z } };
#pragma unroll
    for (int k = 0; k < 4; ++k) {
        const int koff = k * 32 + (lane >> 4) * 8;
        bf16x8 a[2], b[2];
        a[0] = load_row8<false>(agts, r0, koff);
        a[1] = load_row8<false>(agts, r1, koff);
#pragma unroll
        for (int n = 0; n < 2; ++n) {
            int wr = wave * 32 + n * 16 + (lane & 15);
            b[n] = *(const bf16x8*)(wa_bf + (size_t)wr * NCH + koff);
        }
#pragma unroll
        for (int m = 0; m < 2; ++m)
#pragma unroll
            for (int n = 0; n < 2; ++n)
                acc[m][n] = __builtin_amdgcn_mfma_f32_16x16x32_bf16(a[m], b[n], acc[m][n], 0, 0, 0);
    }
#pragma unroll
    for (int m = 0; m < 2; ++m)
#pragma unroll
        for (int n = 0; n < 2; ++n)
#pragma unroll
            for (int j = 0; j < 4; ++j) {
                int r = m * 16 + ((lane >> 4) << 2) + j;
                int ng = n0 + r;
                if (ng < N)
                    outbuf[(size_t)ng * NCH + wave * 32 + n * 16 + (lane & 15)] = acc[m][n][j];
            }
}

// ---------------------------------------------------------------------------
// node_post: relu(GN(out)) -> GN(out @ w_l^T) -> relu(+ res), in place, MFMA.
// ---------------------------------------------------------------------------
__global__ __launch_bounds__(256) void node_post_kernel(
    float* __restrict__ outbuf, const float* __restrict__ agts,
    const float* __restrict__ g_n, const float* __restrict__ bt_n,
    const unsigned short* __restrict__ wl_bf,
    const float* __restrict__ g_l, const float* __restrict__ bt_l, int N)
{
    const int t = threadIdx.x;
    const int lane = t & 63, wave = t >> 6;
    const int n0 = blockIdx.x * NB;

    __shared__ unsigned short bfP[NB * NCH];
    __shared__ __align__(16) float red_s[NB][4];
    __shared__ __align__(16) float red_q[NB][4];

    // ---- GN1 (channel-owner layout)
    const int c = t & 127, rh = t >> 7;
    float v[16];
#pragma unroll
    for (int i = 0; i < 16; ++i) {
        int n = n0 + rh * 16 + i; if (n >= N) n = N - 1;
        v[i] = outbuf[(size_t)n * NCH + c];
    }
#pragma unroll
    for (int i = 0; i < 16; ++i) {
        float s = v[i], q = v[i] * v[i];
        for (int off = 32; off > 0; off >>= 1) {
            s += __shfl_down(s, off);
            q += __shfl_down(q, off);
        }
        if (lane == 0) { red_s[rh * 16 + i][wave & 1] = s; red_q[rh * 16 + i][wave & 1] = q; }
    }
    __syncthreads();
    {
        const float g = g_n[c], b = bt_n[c];
#pragma unroll
        for (int i = 0; i < 16; ++i) {
            int r = rh * 16 + i;
            float s = red_s[r][0] + red_s[r][1];
            float q = red_q[r][0] + red_q[r][1];
            float m_  = s * (1.f / NCH);
            float var = q * (1.f / NCH) - m_ * m_;
            float rrs = rsqrtf(var + 1e-5f);
            float val = fmaxf((v[i] - m_) * rrs * g + b, 0.f);
            unsigned int pv = f2bf(val);
            unsigned int ov = (unsigned int)__shfl_xor((int)pv, 1);
            if (!(c & 1)) {
                int byte = (r * 256 + c * 2) ^ ((r & 7) << 4);
                *(unsigned int*)((char*)bfP + byte) = (pv & 0xffffu) | (ov << 16);
            }
        }
    }
    __syncthreads();

    // ---- MFMA: h = gn1 @ w_l^T
    const f32x4 z = { 0.f, 0.f, 0.f, 0.f };
    f32x4 acc[2][2] = { { z, z }, { z, z } };
    gemm_k128_lds(bfP, wl_bf, lane, wave, acc);

    // ---- GN2 (no relu) + residual + relu, store in place
    float mu[2][4], rs[2][4];
    gn_frag_stats(acc, red_s, red_q, t, mu, rs);
    const int c0 = wave * 32 + (lane & 15);
    const float g0 = g_l[c0],      b0 = bt_l[c0];
    const float g1 = g_l[c0 + 16], b1 = bt_l[c0 + 16];
#pragma unroll
    for (int m = 0; m < 2; ++m)
#pragma unroll
        for (int j = 0; j < 4; ++j) {
            int r = m * 16 + ((lane >> 4) << 2) + j;
            int ng = n0 + r;
            if (ng < N) {
                float v0 = (acc[m][0][j] - mu[m][j]) * rs[m][j] * g0 + b0;
                float v1 = (acc[m][1][j] - mu[m][j]) * rs[m][j] * g1 + b1;
                v0 = fmaxf(v0 + agts[(size_t)ng * NCH + c0], 0.f);
                v1 = fmaxf(v1 + agts[(size_t)ng * NCH + c0 + 16], 0.f);
                outbuf[(size_t)ng * NCH + c0]      = v0;
                outbuf[(size_t)ng * NCH + c0 + 16] = v1;
            }
        }
}

// ---------------------------------------------------------------------------
extern "C" void kernel_launch(void* const* d_in, const int* in_sizes, int n_in,
                              void* d_out, int out_size, void* d_ws, size_t ws_size,
                              hipStream_t stream) {
    const float* agts     = (const float*)d_in[0];
    const float* ctx      = (const float*)d_in[1];
    const float* agt_ctrs = (const float*)d_in[2];
    const float* ctx_ctrs = (const float*)d_in[3];
    const int*   hi       = (const int*)d_in[4];
    const int*   wi       = (const int*)d_in[5];
    const float* w_d1     = (const float*)d_in[6];
    const float* b_d1     = (const float*)d_in[7];
    const float* w_d2     = (const float*)d_in[8];
    const float* g_d2     = (const float*)d_in[9];
    const float* bt_d2    = (const float*)d_in[10];
    const float* w_q      = (const float*)d_in[11];
    const float* g_q      = (const float*)d_in[12];
    const float* bt_q     = (const float*)d_in[13];
    const float* w_c1     = (const float*)d_in[14];
    const float* g_c1     = (const float*)d_in[15];
    const float* bt_c1    = (const float*)d_in[16];
    const float* w_c2     = (const float*)d_in[17];
    const float* w_a      = (const float*)d_in[18];
    const float* g_n      = (const float*)d_in[19];
    const float* bt_n     = (const float*)d_in[20];
    const float* w_l      = (const float*)d_in[21];
    const float* g_l      = (const float*)d_in[22];
    const float* bt_l     = (const float*)d_in[23];

    const int N = in_sizes[0] / NCH;
    const int E = in_sizes[4];

    float* outbuf = (float*)d_out;                 // [N,128] f32 accumulator

    unsigned short* wbf = (unsigned short*)d_ws;   // 131072 bf16 weights
    unsigned short* cbf = wbf + 131072;            // ctx bf16 cache
    unsigned short* qbf = cbf + (size_t)N * NCH;   // q   bf16 cache
    const size_t need = 262144ull + (size_t)N * NCH * 4ull;  // bytes
    const bool big = (d_ws != nullptr) && (ws_size >= need);

    const int nb_nodes = (N + NB - 1) / NB;
    const int nb_edges = (E + EB - 1) / EB;

    convert_weights_kernel<<<512, 256, 0, stream>>>(w_d2, w_q, w_c1, w_c2, w_a, w_l, wbf);

    if (big) {
        convert_ctx_kernel<<<1024, 256, 0, stream>>>(ctx, cbf, N * NCH / 4);
        node_prep_kernel<<<nb_nodes, 256, 0, stream>>>(
            agts, wbf + 98304, wbf + 16384, g_q, bt_q, outbuf, qbf, N);
        edge_kernel<true><<<nb_edges, 256, 0, stream>>>(
            qbf, cbf, agt_ctrs, ctx_ctrs, hi, wi,
            w_d1, b_d1, g_d2, bt_d2, g_q, bt_q, g_c1, bt_c1,
            wbf, outbuf, E);
    } else {
        node_init_kernel<<<nb_nodes, 256, 0, stream>>>(agts, wbf + 98304, outbuf, N);
        edge_kernel<false><<<nb_edges, 256, 0, stream>>>(
            agts, ctx, agt_ctrs, ctx_ctrs, hi, wi,
            w_d1, b_d1, g_d2, bt_d2, g_q, bt_q, g_c1, bt_c1,
            wbf, outbuf, E);
    }
    node_post_kernel<<<nb_nodes, 256, 0, stream>>>(
        outbuf, agts, g_n, bt_n, wbf + 114688, g_l, bt_l, N);
}

// Round 8
// 324.735 us; speedup vs baseline: 1.2852x; 1.0029x over previous
//
#include <hip/hip_runtime.h>
#include <hip/hip_bf16.h>

#define NCH 128      // n_agt == n_ctx
#define EB  32       // edges per block (edge kernel)
#define NB  32       // nodes per block (node kernels)

typedef __attribute__((ext_vector_type(8))) short bf16x8;
typedef __attribute__((ext_vector_type(4))) float f32x4;

__device__ inline unsigned short f2bf(float v) {
    __hip_bfloat16 h = __float2bfloat16(v);
    return __builtin_bit_cast(unsigned short, h);
}

__device__ inline bf16x8 cvt8(const float* __restrict__ p) {
    bf16x8 r;
#pragma unroll
    for (int i = 0; i < 8; ++i) r[i] = (short)f2bf(p[i]);
    return r;
}

template<bool BF>
__device__ inline bf16x8 load_row8(const void* __restrict__ src, int node, int koff) {
    if constexpr (BF)
        return *(const bf16x8*)((const unsigned short*)src + (size_t)node * NCH + koff);
    else
        return cvt8((const float*)src + (size_t)node * NCH + koff);
}

// ---------------------------------------------------------------------------
// Weight conversion: Wd2 | Wq | Wc1 | Wc2 | Wa | Wl  (131072 bf16 = 256 KB)
// ---------------------------------------------------------------------------
__global__ __launch_bounds__(256) void convert_weights_kernel(
    const float* __restrict__ w_d2, const float* __restrict__ w_q,
    const float* __restrict__ w_c1, const float* __restrict__ w_c2,
    const float* __restrict__ w_a,  const float* __restrict__ w_l,
    unsigned short* __restrict__ out)
{
    int i = blockIdx.x * 256 + threadIdx.x;
    const float* src; int off;
    if      (i < 16384)  { src = w_d2; off = i; }
    else if (i < 32768)  { src = w_q;  off = i - 16384; }
    else if (i < 81920)  { src = w_c1; off = i - 32768; }
    else if (i < 98304)  { src = w_c2; off = i - 81920; }
    else if (i < 114688) { src = w_a;  off = i - 98304; }
    else if (i < 131072) { src = w_l;  off = i - 114688; }
    else return;
    out[i] = f2bf(src[off]);
}

// ---------------------------------------------------------------------------
// ctx -> bf16 cache (vectorized, grid-stride)
// ---------------------------------------------------------------------------
__global__ __launch_bounds__(256) void convert_ctx_kernel(
    const float* __restrict__ c, unsigned short* __restrict__ cbf, int nq)
{
    const int stride = gridDim.x * blockDim.x;
    for (int i = blockIdx.x * blockDim.x + threadIdx.x; i < nq; i += stride) {
        float4 v = ((const float4*)c)[i];
        ushort4 o = { f2bf(v.x), f2bf(v.y), f2bf(v.z), f2bf(v.w) };
        ((ushort4*)cbf)[i] = o;
    }
}

// ---------------------------------------------------------------------------
// K=128 GEMM step, A from swizzled bf16 LDS tile (32 rows), B = W rows (global bf16)
// ---------------------------------------------------------------------------
__device__ inline void gemm_k128_lds(const unsigned short* __restrict__ A,
                                     const unsigned short* __restrict__ W,
                                     int lane, int wave, f32x4 (&acc)[2][2])
{
#pragma unroll
    for (int k = 0; k < 4; ++k) {
        const int koff = k * 32 + (lane >> 4) * 8;
        bf16x8 a[2], b[2];
#pragma unroll
        for (int m = 0; m < 2; ++m) {
            int r = m * 16 + (lane & 15);
            int byte = (r * 256 + koff * 2) ^ ((r & 7) << 4);
            a[m] = *(const bf16x8*)((const char*)A + byte);
        }
#pragma unroll
        for (int n = 0; n < 2; ++n) {
            int wr = wave * 32 + n * 16 + (lane & 15);
            b[n] = *(const bf16x8*)(W + (size_t)wr * NCH + koff);
        }
#pragma unroll
        for (int m = 0; m < 2; ++m)
#pragma unroll
            for (int n = 0; n < 2; ++n)
                acc[m][n] = __builtin_amdgcn_mfma_f32_16x16x32_bf16(a[m], b[n], acc[m][n], 0, 0, 0);
    }
}

// ---------------------------------------------------------------------------
// Fragment-domain GroupNorm stats for a 32x128 tile held as C-fragments.
// One barrier; it also orders all waves' prior LDS reads before later packs.
// ---------------------------------------------------------------------------
__device__ inline void gn_frag_stats(const f32x4 (&acc)[2][2],
                                     float (*red_s)[4], float (*red_q)[4],
                                     int t, float (&mu)[2][4], float (&rs)[2][4])
{
    const int lane = t & 63, wave = t >> 6;
    float s[2][4], q[2][4];
#pragma unroll
    for (int m = 0; m < 2; ++m)
#pragma unroll
        for (int j = 0; j < 4; ++j) {
            float sv = acc[m][0][j] + acc[m][1][j];
            float qv = acc[m][0][j] * acc[m][0][j] + acc[m][1][j] * acc[m][1][j];
#pragma unroll
            for (int off = 1; off < 16; off <<= 1) {
                sv += __shfl_xor(sv, off);
                qv += __shfl_xor(qv, off);
            }
            s[m][j] = sv; q[m][j] = qv;
        }
    if ((lane & 15) == 0) {
        const int rg = lane >> 4;
#pragma unroll
        for (int m = 0; m < 2; ++m)
#pragma unroll
            for (int j = 0; j < 4; ++j) {
                int r = m * 16 + rg * 4 + j;
                red_s[r][wave] = s[m][j];
                red_q[r][wave] = q[m][j];
            }
    }
    __syncthreads();
#pragma unroll
    for (int m = 0; m < 2; ++m)
#pragma unroll
        for (int j = 0; j < 4; ++j) {
            int r = m * 16 + ((lane >> 4) << 2) + j;
            float4 sv = *(const float4*)red_s[r];
            float4 qv = *(const float4*)red_q[r];
            float ssum = (sv.x + sv.y) + (sv.z + sv.w);
            float qsum = (qv.x + qv.y) + (qv.z + qv.w);
            float m_  = ssum * (1.f / NCH);
            float var = qsum * (1.f / NCH) - m_ * m_;
            mu[m][j] = m_;
            rs[m][j] = rsqrtf(var + 1e-5f);
        }
}

// Apply GN + ReLU to fragments and pack bf16 into swizzled LDS tile dst.
__device__ inline void gn_pack_store(const f32x4 (&acc)[2][2],
                                     const float (&mu)[2][4], const float (&rs)[2][4],
                                     const float* __restrict__ gamma,
                                     const float* __restrict__ beta,
                                     unsigned short* __restrict__ dst, int t)
{
    const int lane = t & 63, wave = t >> 6;
    const int c0 = wave * 32 + (lane & 15);
    const float g0 = gamma[c0],      b0 = beta[c0];
    const float g1 = gamma[c0 + 16], b1 = beta[c0 + 16];
#pragma unroll
    for (int m = 0; m < 2; ++m)
#pragma unroll
        for (int j = 0; j < 4; ++j) {
            int r = m * 16 + ((lane >> 4) << 2) + j;
            float v0 = fmaxf((acc[m][0][j] - mu[m][j]) * rs[m][j] * g0 + b0, 0.f);
            float v1 = fmaxf((acc[m][1][j] - mu[m][j]) * rs[m][j] * g1 + b1, 0.f);
            unsigned int p0 = f2bf(v0), p1 = f2bf(v1);
            unsigned int o0 = (unsigned int)__shfl_xor((int)p0, 1);
            unsigned int o1 = (unsigned int)__shfl_xor((int)p1, 1);
            if (!(lane & 1)) {
                int cb = c0 * 2;
                int byte0 = (r * 256 + cb) ^ ((r & 7) << 4);
                int byte1 = (r * 256 + cb + 32) ^ ((r & 7) << 4);
                *(unsigned int*)((char*)dst + byte0) = (p0 & 0xffffu) | (o0 << 16);
                *(unsigned int*)((char*)dst + byte1) = (p1 & 0xffffu) | (o1 << 16);
            }
        }
    __syncthreads();
}

// ---------------------------------------------------------------------------
// node_prep: out = agts @ Wa^T (f32)  AND  qbf = relu(GN(agts @ Wq^T)) (bf16),
// sharing the A-fragment loads. 32 nodes/block, reads f32 agts directly.
// ---------------------------------------------------------------------------
__global__ __launch_bounds__(256) void node_prep_kernel(
    const float* __restrict__ agts,
    const unsigned short* __restrict__ wa_bf, const unsigned short* __restrict__ wq_bf,
    const float* __restrict__ g_q, const float* __restrict__ bt_q,
    float* __restrict__ outbuf, unsigned short* __restrict__ qbf, int N)
{
    const int t = threadIdx.x;
    const int lane = t & 63, wave = t >> 6;
    const int n0 = blockIdx.x * NB;

    __shared__ __align__(16) float red_s[NB][4];
    __shared__ __align__(16) float red_q[NB][4];

    int r0 = n0 + (lane & 15);      if (r0 >= N) r0 = N - 1;
    int r1 = n0 + 16 + (lane & 15); if (r1 >= N) r1 = N - 1;

    const f32x4 z = { 0.f, 0.f, 0.f, 0.f };
    f32x4 accO[2][2] = { { z, z }, { z, z } };
    f32x4 accQ[2][2] = { { z, z }, { z, z } };
#pragma unroll
    for (int k = 0; k < 4; ++k) {
        const int koff = k * 32 + (lane >> 4) * 8;
        bf16x8 a[2], bo[2], bq[2];
        a[0] = load_row8<false>(agts, r0, koff);
        a[1] = load_row8<false>(agts, r1, koff);
#pragma unroll
        for (int n = 0; n < 2; ++n) {
            int wr = wave * 32 + n * 16 + (lane & 15);
            bo[n] = *(const bf16x8*)(wa_bf + (size_t)wr * NCH + koff);
            bq[n] = *(const bf16x8*)(wq_bf + (size_t)wr * NCH + koff);
        }
#pragma unroll
        for (int m = 0; m < 2; ++m)
#pragma unroll
            for (int n = 0; n < 2; ++n) {
                accO[m][n] = __builtin_amdgcn_mfma_f32_16x16x32_bf16(a[m], bo[n], accO[m][n], 0, 0, 0);
                accQ[m][n] = __builtin_amdgcn_mfma_f32_16x16x32_bf16(a[m], bq[n], accQ[m][n], 0, 0, 0);
            }
    }
    // f32 store of the Wa product
#pragma unroll
    for (int m = 0; m < 2; ++m)
#pragma unroll
        for (int n = 0; n < 2; ++n)
#pragma unroll
            for (int j = 0; j < 4; ++j) {
                int r = m * 16 + ((lane >> 4) << 2) + j;
                int ng = n0 + r;
                if (ng < N)
                    outbuf[(size_t)ng * NCH + wave * 32 + n * 16 + (lane & 15)] = accO[m][n][j];
            }
    // GN + relu + bf16 pack of the Wq product -> global qbf (row-major)
    float mu[2][4], rs[2][4];
    gn_frag_stats(accQ, red_s, red_q, t, mu, rs);
    const int c0 = wave * 32 + (lane & 15);
    const float g0 = g_q[c0],      b0 = bt_q[c0];
    const float g1 = g_q[c0 + 16], b1 = bt_q[c0 + 16];
#pragma unroll
    for (int m = 0; m < 2; ++m)
#pragma unroll
        for (int j = 0; j < 4; ++j) {
            int r = m * 16 + ((lane >> 4) << 2) + j;
            int ng = n0 + r;
            float v0 = fmaxf((accQ[m][0][j] - mu[m][j]) * rs[m][j] * g0 + b0, 0.f);
            float v1 = fmaxf((accQ[m][1][j] - mu[m][j]) * rs[m][j] * g1 + b1, 0.f);
            unsigned int p0 = f2bf(v0), p1 = f2bf(v1);
            unsigned int o0 = (unsigned int)__shfl_xor((int)p0, 1);
            unsigned int o1 = (unsigned int)__shfl_xor((int)p1, 1);
            if (!(lane & 1) && ng < N) {
                unsigned int* rowp = (unsigned int*)((char*)qbf + (size_t)ng * 256);
                rowp[c0 >> 1]        = (p0 & 0xffffu) | (o0 << 16);
                rowp[(c0 + 16) >> 1] = (p1 & 0xffffu) | (o1 << 16);
            }
        }
}

// ---------------------------------------------------------------------------
// Fused edge pipeline (MFMA), 3 LDS tiles.
// __launch_bounds__(256, 8): force VGPR <= 64 (cross the m69 wave cliff);
// LDS (26 KB) then caps residency at 6 blocks/CU (24 waves) vs 4 before.
// ---------------------------------------------------------------------------
template<bool BIG>
__global__ __launch_bounds__(256, 8) void edge_kernel(
    const void* __restrict__ qsrc, const void* __restrict__ ctx_nb,
    const float* __restrict__ agt_ctrs, const float* __restrict__ ctx_ctrs,
    const int* __restrict__ hi, const int* __restrict__ wi,
    const float* __restrict__ w_d1, const float* __restrict__ b_d1,
    const float* __restrict__ g_d2, const float* __restrict__ bt_d2,
    const float* __restrict__ g_q, const float* __restrict__ bt_q,
    const float* __restrict__ g_c1, const float* __restrict__ bt_c1,
    const unsigned short* __restrict__ wbf,
    float* __restrict__ outbuf, int E)
{
    const int t = threadIdx.x;
    const int lane = t & 63;
    const int wave = t >> 6;
    const int e0 = blockIdx.x * EB;

    __shared__ unsigned short bfQ[EB * NCH];
    __shared__ unsigned short bfD[EB * NCH];
    __shared__ unsigned short bfX[EB * NCH];
    __shared__ __align__(16) float red_s[EB][4];
    __shared__ __align__(16) float red_q[EB][4];
    __shared__ int   sh_h[EB], sh_w[EB];
    __shared__ float sh_dx[EB], sh_dy[EB];

    const unsigned short* Wd2 = wbf;
    const unsigned short* Wq  = wbf + 16384;
    const unsigned short* Wc1 = wbf + 32768;
    const unsigned short* Wc2 = wbf + 81920;

    if (t < EB) {
        int e = e0 + t; if (e >= E) e = E - 1;
        int h = hi[e], w = wi[e];
        sh_h[t] = h; sh_w[t] = w;
        sh_dx[t] = agt_ctrs[2 * h]     - ctx_ctrs[2 * w];
        sh_dy[t] = agt_ctrs[2 * h + 1] - ctx_ctrs[2 * w + 1];
    }
    __syncthreads();

    // ---- stage q/agts -> bfQ, ctx -> bfX (coalesced 16B chunks) ----
    {
        const int r  = t >> 3;
        const int cc = t & 7;
        const int h = sh_h[r], w = sh_w[r];
#pragma unroll
        for (int half = 0; half < 2; ++half) {
            int c = cc + half * 8;
            bf16x8 qv = load_row8<BIG>(qsrc, h, c * 8);
            bf16x8 xv = load_row8<BIG>(ctx_nb, w, c * 8);
            int byte = (r * 256 + c * 16) ^ ((r & 7) << 4);
            *(bf16x8*)((char*)bfQ + byte) = qv;
            *(bf16x8*)((char*)bfX + byte) = xv;
        }
    }
    // ---- d1 = relu(w_d1 . [dx,dy] + b_d1) -> bfD ----
    {
        const int c = t & 127, rh = t >> 7;
        const float wa = w_d1[2 * c], wb = w_d1[2 * c + 1], bb = b_d1[c];
#pragma unroll
        for (int i = 0; i < 16; ++i) {
            int r = rh * 16 + i;
            float v = fmaxf(fmaf(wa, sh_dx[r], fmaf(wb, sh_dy[r], bb)), 0.f);
            unsigned int pv = f2bf(v);
            unsigned int ov = (unsigned int)__shfl_xor((int)pv, 1);
            if (!(c & 1)) {
                int byte = (r * 256 + c * 2) ^ ((r & 7) << 4);
                *(unsigned int*)((char*)bfD + byte) = (pv & 0xffffu) | (ov << 16);
            }
        }
    }
    __syncthreads();

    const f32x4 z = { 0.f, 0.f, 0.f, 0.f };
    f32x4 acc[2][2];
    float mu[2][4], rs[2][4];

    // ---- d2 = relu(GN(d1 @ Wd2^T)) -> bfD ----
    acc[0][0] = z; acc[0][1] = z; acc[1][0] = z; acc[1][1] = z;
    gemm_k128_lds(bfD, Wd2, lane, wave, acc);
    gn_frag_stats(acc, red_s, red_q, t, mu, rs);
    gn_pack_store(acc, mu, rs, g_d2, bt_d2, bfD, t);

    if constexpr (!BIG) {
        // ---- q = relu(GN(agts[hi] @ Wq^T)) -> bfQ ----
        acc[0][0] = z; acc[0][1] = z; acc[1][0] = z; acc[1][1] = z;
        gemm_k128_lds(bfQ, Wq, lane, wave, acc);
        gn_frag_stats(acc, red_s, red_q, t, mu, rs);
        gn_pack_store(acc, mu, rs, g_q, bt_q, bfQ, t);
    }

    // ---- c1 = relu(GN([d2|q|ctx] @ Wc1^T)) -> bfD ----  (K = 384)
    acc[0][0] = z; acc[0][1] = z; acc[1][0] = z; acc[1][1] = z;
#pragma unroll
    for (int kt = 0; kt < 12; ++kt) {
        const unsigned short* Ab = (kt < 4) ? bfD : (kt < 8) ? bfQ : bfX;
        const int koff = (kt & 3) * 32 + (lane >> 4) * 8;
        bf16x8 a[2], b[2];
#pragma unroll
        for (int m = 0; m < 2; ++m) {
            int r = m * 16 + (lane & 15);
            int byte = (r * 256 + koff * 2) ^ ((r & 7) << 4);
            a[m] = *(const bf16x8*)((const char*)Ab + byte);
        }
#pragma unroll
        for (int n = 0; n < 2; ++n) {
            int wr = wave * 32 + n * 16 + (lane & 15);
            b[n] = *(const bf16x8*)(Wc1 + (size_t)wr * 384 + kt * 32 + (lane >> 4) * 8);
        }
#pragma unroll
        for (int m = 0; m < 2; ++m)
#pragma unroll
            for (int n = 0; n < 2; ++n)
                acc[m][n] = __builtin_amdgcn_mfma_f32_16x16x32_bf16(a[m], b[n], acc[m][n], 0, 0, 0);
    }
    gn_frag_stats(acc, red_s, red_q, t, mu, rs);
    gn_pack_store(acc, mu, rs, g_c1, bt_c1, bfD, t);

    // ---- e = c1 @ Wc2^T ; scatter-add to outbuf[hi] ----
    acc[0][0] = z; acc[0][1] = z; acc[1][0] = z; acc[1][1] = z;
    gemm_k128_lds(bfD, Wc2, lane, wave, acc);
#pragma unroll
    for (int m = 0; m < 2; ++m)
#pragma unroll
        for (int n = 0; n < 2; ++n)
#pragma unroll
            for (int j = 0; j < 4; ++j) {
                int r = m * 16 + ((lane >> 4) << 2) + j;
                if (e0 + r < E)
                    atomicAdd(&outbuf[(size_t)sh_h[r] * NCH + wave * 32 + n * 16 + (lane & 15)],
                              acc[m][n][j]);
            }
}

// ---------------------------------------------------------------------------
// node_init (fallback only): out = agts @ w_a^T via MFMA.
// ---------------------------------------------------------------------------
__global__ __launch_bounds__(256) void node_init_kernel(
    const float* __restrict__ agts, const unsigned short* __restrict__ wa_bf,
    float* __restrict__ outbuf, int N)
{
    const int t = threadIdx.x;
    const int lane = t & 63, wave = t >> 6;
    const int n0 = blockIdx.x * NB;

    int r0 = n0 + (lane & 15);      if (r0 >= N) r0 = N - 1;
    int r1 = n0 + 16 + (lane & 15); if (r1 >= N) r1 = N - 1;

    const f32x4 z = { 0.f, 0.f, 0.f, 0.f };
    f32x4 acc[2][2] = { { z, z }, { z, z } };
#pragma unroll
    for (int k = 0; k < 4; ++k) {
        const int koff = k * 32 + (lane >> 4) * 8;
        bf16x8 a[2], b[2];
        a[0] = load_row8<false>(agts, r0, koff);
        a[1] = load_row8<false>(agts, r1, koff);
#pragma unroll
        for (int n = 0; n < 2; ++n) {
            int wr = wave * 32 + n * 16 + (lane & 15);
            b[n] = *(const bf16x8*)(wa_bf + (size_t)wr * NCH + koff);
        }
#pragma unroll
        for (int m = 0; m < 2; ++m)
#pragma unroll
            for (int n = 0; n < 2; ++n)
                acc[m][n] = __builtin_amdgcn_mfma_f32_16x16x32_bf16(a[m], b[n], acc[m][n], 0, 0, 0);
    }
#pragma unroll
    for (int m = 0; m < 2; ++m)
#pragma unroll
        for (int n = 0; n < 2; ++n)
#pragma unroll
            for (int j = 0; j < 4; ++j) {
                int r = m * 16 + ((lane >> 4) << 2) + j;
                int ng = n0 + r;
                if (ng < N)
                    outbuf[(size_t)ng * NCH + wave * 32 + n * 16 + (lane & 15)] = acc[m][n][j];
            }
}

// ---------------------------------------------------------------------------
// node_post: relu(GN(out)) -> GN(out @ w_l^T) -> relu(+ res), in place, MFMA.
// ---------------------------------------------------------------------------
__global__ __launch_bounds__(256) void node_post_kernel(
    float* __restrict__ outbuf, const float* __restrict__ agts,
    const float* __restrict__ g_n, const float* __restrict__ bt_n,
    const unsigned short* __restrict__ wl_bf,
    const float* __restrict__ g_l, const float* __restrict__ bt_l, int N)
{
    const int t = threadIdx.x;
    const int lane = t & 63, wave = t >> 6;
    const int n0 = blockIdx.x * NB;

    __shared__ unsigned short bfP[NB * NCH];
    __shared__ __align__(16) float red_s[NB][4];
    __shared__ __align__(16) float red_q[NB][4];

    // ---- GN1 (channel-owner layout)
    const int c = t & 127, rh = t >> 7;
    float v[16];
#pragma unroll
    for (int i = 0; i < 16; ++i) {
        int n = n0 + rh * 16 + i; if (n >= N) n = N - 1;
        v[i] = outbuf[(size_t)n * NCH + c];
    }
#pragma unroll
    for (int i = 0; i < 16; ++i) {
        float s = v[i], q = v[i] * v[i];
        for (int off = 32; off > 0; off >>= 1) {
            s += __shfl_down(s, off);
            q += __shfl_down(q, off);
        }
        if (lane == 0) { red_s[rh * 16 + i][wave & 1] = s; red_q[rh * 16 + i][wave & 1] = q; }
    }
    __syncthreads();
    {
        const float g = g_n[c], b = bt_n[c];
#pragma unroll
        for (int i = 0; i < 16; ++i) {
            int r = rh * 16 + i;
            float s = red_s[r][0] + red_s[r][1];
            float q = red_q[r][0] + red_q[r][1];
            float m_  = s * (1.f / NCH);
            float var = q * (1.f / NCH) - m_ * m_;
            float rrs = rsqrtf(var + 1e-5f);
            float val = fmaxf((v[i] - m_) * rrs * g + b, 0.f);
            unsigned int pv = f2bf(val);
            unsigned int ov = (unsigned int)__shfl_xor((int)pv, 1);
            if (!(c & 1)) {
                int byte = (r * 256 + c * 2) ^ ((r & 7) << 4);
                *(unsigned int*)((char*)bfP + byte) = (pv & 0xffffu) | (ov << 16);
            }
        }
    }
    __syncthreads();

    // ---- MFMA: h = gn1 @ w_l^T
    const f32x4 z = { 0.f, 0.f, 0.f, 0.f };
    f32x4 acc[2][2] = { { z, z }, { z, z } };
    gemm_k128_lds(bfP, wl_bf, lane, wave, acc);

    // ---- GN2 (no relu) + residual + relu, store in place
    float mu[2][4], rs[2][4];
    gn_frag_stats(acc, red_s, red_q, t, mu, rs);
    const int c0 = wave * 32 + (lane & 15);
    const float g0 = g_l[c0],      b0 = bt_l[c0];
    const float g1 = g_l[c0 + 16], b1 = bt_l[c0 + 16];
#pragma unroll
    for (int m = 0; m < 2; ++m)
#pragma unroll
        for (int j = 0; j < 4; ++j) {
            int r = m * 16 + ((lane >> 4) << 2) + j;
            int ng = n0 + r;
            if (ng < N) {
                float v0 = (acc[m][0][j] - mu[m][j]) * rs[m][j] * g0 + b0;
                float v1 = (acc[m][1][j] - mu[m][j]) * rs[m][j] * g1 + b1;
                v0 = fmaxf(v0 + agts[(size_t)ng * NCH + c0], 0.f);
                v1 = fmaxf(v1 + agts[(size_t)ng * NCH + c0 + 16], 0.f);
                outbuf[(size_t)ng * NCH + c0]      = v0;
                outbuf[(size_t)ng * NCH + c0 + 16] = v1;
            }
        }
}

// ---------------------------------------------------------------------------
extern "C" void kernel_launch(void* const* d_in, const int* in_sizes, int n_in,
                              void* d_out, int out_size, void* d_ws, size_t ws_size,
                              hipStream_t stream) {
    const float* agts     = (const float*)d_in[0];
    const float* ctx      = (const float*)d_in[1];
    const float* agt_ctrs = (const float*)d_in[2];
    const float* ctx_ctrs = (const float*)d_in[3];
    const int*   hi       = (const int*)d_in[4];
    const int*   wi       = (const int*)d_in[5];
    const float* w_d1     = (const float*)d_in[6];
    const float* b_d1     = (const float*)d_in[7];
    const float* w_d2     = (const float*)d_in[8];
    const float* g_d2     = (const float*)d_in[9];
    const float* bt_d2    = (const float*)d_in[10];
    const float* w_q      = (const float*)d_in[11];
    const float* g_q      = (const float*)d_in[12];
    const float* bt_q     = (const float*)d_in[13];
    const float* w_c1     = (const float*)d_in[14];
    const float* g_c1     = (const float*)d_in[15];
    const float* bt_c1    = (const float*)d_in[16];
    const float* w_c2     = (const float*)d_in[17];
    const float* w_a      = (const float*)d_in[18];
    const float* g_n      = (const float*)d_in[19];
    const float* bt_n     = (const float*)d_in[20];
    const float* w_l      = (const float*)d_in[21];
    const float* g_l      = (const float*)d_in[22];
    const float* bt_l     = (const float*)d_in[23];

    const int N = in_sizes[0] / NCH;
    const int E = in_sizes[4];

    float* outbuf = (float*)d_out;                 // [N,128] f32 accumulator

    unsigned short* wbf = (unsigned short*)d_ws;   // 131072 bf16 weights
    unsigned short* cbf = wbf + 131072;            // ctx bf16 cache
    unsigned short* qbf = cbf + (size_t)N * NCH;   // q   bf16 cache
    const size_t need = 262144ull + (size_t)N * NCH * 4ull;  // bytes
    const bool big = (d_ws != nullptr) && (ws_size >= need);

    const int nb_nodes = (N + NB - 1) / NB;
    const int nb_edges = (E + EB - 1) / EB;

    convert_weights_kernel<<<512, 256, 0, stream>>>(w_d2, w_q, w_c1, w_c2, w_a, w_l, wbf);

    if (big) {
        convert_ctx_kernel<<<1024, 256, 0, stream>>>(ctx, cbf, N * NCH / 4);
        node_prep_kernel<<<nb_nodes, 256, 0, stream>>>(
            agts, wbf + 98304, wbf + 16384, g_q, bt_q, outbuf, qbf, N);
        edge_kernel<true><<<nb_edges, 256, 0, stream>>>(
            qbf, cbf, agt_ctrs, ctx_ctrs, hi, wi,
            w_d1, b_d1, g_d2, bt_d2, g_q, bt_q, g_c1, bt_c1,
            wbf, outbuf, E);
    } else {
        node_init_kernel<<<nb_nodes, 256, 0, stream>>>(agts, wbf + 98304, outbuf, N);
        edge_kernel<false><<<nb_edges, 256, 0, stream>>>(
            agts, ctx, agt_ctrs, ctx_ctrs, hi, wi,
            w_d1, b_d1, g_d2, bt_d2, g_q, bt_q, g_c1, bt_c1,
            wbf, outbuf, E);
    }
    node_post_kernel<<<nb_nodes, 256, 0, stream>>>(
        outbuf, agts, g_n, bt_n, wbf + 114688, g_l, bt_l, N);
}

// Round 9
// 308.913 us; speedup vs baseline: 1.3510x; 1.0512x over previous
//
#include <hip/hip_runtime.h>
#include <hip/hip_bf16.h>

#define NCH 128      // n_agt == n_ctx
#define EB  32       // edges per block (edge kernel)
#define NB  32       // nodes per block (node kernels)

typedef __attribute__((ext_vector_type(8))) short bf16x8;
typedef __attribute__((ext_vector_type(4))) float f32x4;

__device__ inline unsigned short f2bf(float v) {
    __hip_bfloat16 h = __float2bfloat16(v);
    return __builtin_bit_cast(unsigned short, h);
}
__device__ inline float bf2f(unsigned short u) {
    return __builtin_bit_cast(float, (unsigned int)u << 16);
}

__device__ inline bf16x8 cvt8(const float* __restrict__ p) {
    bf16x8 r;
#pragma unroll
    for (int i = 0; i < 8; ++i) r[i] = (short)f2bf(p[i]);
    return r;
}

template<bool BF>
__device__ inline bf16x8 load_row8(const void* __restrict__ src, int node, int koff) {
    if constexpr (BF)
        return *(const bf16x8*)((const unsigned short*)src + (size_t)node * NCH + koff);
    else
        return cvt8((const float*)src + (size_t)node * NCH + koff);
}

// ---------------------------------------------------------------------------
// Weight conversion / re-layout to bf16 (131072 bf16 = 256 KB):
//  0:      Wd2  [128x128]
//  16384:  Wq   [128x128]
//  32768:  Wc1d [128x128]  = w_c1[:, 0:128]
//  49152:  Wc1q [128x128]  = w_c1[:, 128:256]
//  65536:  Wc1x [128x128]  = w_c1[:, 256:384]
//  81920:  Wc2  [128x128]
//  98304:  Wa   [128x128]
//  114688: Wl   [128x128]
// ---------------------------------------------------------------------------
__global__ __launch_bounds__(256) void convert_weights_kernel(
    const float* __restrict__ w_d2, const float* __restrict__ w_q,
    const float* __restrict__ w_c1, const float* __restrict__ w_c2,
    const float* __restrict__ w_a,  const float* __restrict__ w_l,
    unsigned short* __restrict__ out)
{
    int i = blockIdx.x * 256 + threadIdx.x;
    if (i >= 131072) return;
    const float* src; int off;
    if      (i < 16384)  { src = w_d2; off = i; }
    else if (i < 32768)  { src = w_q;  off = i - 16384; }
    else if (i < 49152)  { int j = i - 32768; src = w_c1; off = (j >> 7) * 384 + (j & 127); }
    else if (i < 65536)  { int j = i - 49152; src = w_c1; off = (j >> 7) * 384 + 128 + (j & 127); }
    else if (i < 81920)  { int j = i - 65536; src = w_c1; off = (j >> 7) * 384 + 256 + (j & 127); }
    else if (i < 98304)  { src = w_c2; off = i - 81920; }
    else if (i < 114688) { src = w_a;  off = i - 98304; }
    else                 { src = w_l;  off = i - 114688; }
    out[i] = f2bf(src[off]);
}

// ---------------------------------------------------------------------------
// K=128 GEMM step, A from swizzled bf16 LDS tile (32 rows), B = W rows (global bf16)
// ---------------------------------------------------------------------------
__device__ inline void gemm_k128_lds(const unsigned short* __restrict__ A,
                                     const unsigned short* __restrict__ W,
                                     int lane, int wave, f32x4 (&acc)[2][2])
{
#pragma unroll
    for (int k = 0; k < 4; ++k) {
        const int koff = k * 32 + (lane >> 4) * 8;
        bf16x8 a[2], b[2];
#pragma unroll
        for (int m = 0; m < 2; ++m) {
            int r = m * 16 + (lane & 15);
            int byte = (r * 256 + koff * 2) ^ ((r & 7) << 4);
            a[m] = *(const bf16x8*)((const char*)A + byte);
        }
#pragma unroll
        for (int n = 0; n < 2; ++n) {
            int wr = wave * 32 + n * 16 + (lane & 15);
            b[n] = *(const bf16x8*)(W + (size_t)wr * NCH + koff);
        }
#pragma unroll
        for (int m = 0; m < 2; ++m)
#pragma unroll
            for (int n = 0; n < 2; ++n)
                acc[m][n] = __builtin_amdgcn_mfma_f32_16x16x32_bf16(a[m], b[n], acc[m][n], 0, 0, 0);
    }
}

// ---------------------------------------------------------------------------
// Fragment-domain GroupNorm stats for a 32x128 tile held as C-fragments.
// One barrier; it also orders all waves' prior LDS reads before later packs.
// ---------------------------------------------------------------------------
__device__ inline void gn_frag_stats(const f32x4 (&acc)[2][2],
                                     float (*red_s)[4], float (*red_q)[4],
                                     int t, float (&mu)[2][4], float (&rs)[2][4])
{
    const int lane = t & 63, wave = t >> 6;
    float s[2][4], q[2][4];
#pragma unroll
    for (int m = 0; m < 2; ++m)
#pragma unroll
        for (int j = 0; j < 4; ++j) {
            float sv = acc[m][0][j] + acc[m][1][j];
            float qv = acc[m][0][j] * acc[m][0][j] + acc[m][1][j] * acc[m][1][j];
#pragma unroll
            for (int off = 1; off < 16; off <<= 1) {
                sv += __shfl_xor(sv, off);
                qv += __shfl_xor(qv, off);
            }
            s[m][j] = sv; q[m][j] = qv;
        }
    if ((lane & 15) == 0) {
        const int rg = lane >> 4;
#pragma unroll
        for (int m = 0; m < 2; ++m)
#pragma unroll
            for (int j = 0; j < 4; ++j) {
                int r = m * 16 + rg * 4 + j;
                red_s[r][wave] = s[m][j];
                red_q[r][wave] = q[m][j];
            }
    }
    __syncthreads();
#pragma unroll
    for (int m = 0; m < 2; ++m)
#pragma unroll
        for (int j = 0; j < 4; ++j) {
            int r = m * 16 + ((lane >> 4) << 2) + j;
            float4 sv = *(const float4*)red_s[r];
            float4 qv = *(const float4*)red_q[r];
            float ssum = (sv.x + sv.y) + (sv.z + sv.w);
            float qsum = (qv.x + qv.y) + (qv.z + qv.w);
            float m_  = ssum * (1.f / NCH);
            float var = qsum * (1.f / NCH) - m_ * m_;
            mu[m][j] = m_;
            rs[m][j] = rsqrtf(var + 1e-5f);
        }
}

// Apply GN + ReLU to fragments and pack bf16 into swizzled LDS tile dst.
__device__ inline void gn_pack_store(const f32x4 (&acc)[2][2],
                                     const float (&mu)[2][4], const float (&rs)[2][4],
                                     const float* __restrict__ gamma,
                                     const float* __restrict__ beta,
                                     unsigned short* __restrict__ dst, int t)
{
    const int lane = t & 63, wave = t >> 6;
    const int c0 = wave * 32 + (lane & 15);
    const float g0 = gamma[c0],      b0 = beta[c0];
    const float g1 = gamma[c0 + 16], b1 = beta[c0 + 16];
#pragma unroll
    for (int m = 0; m < 2; ++m)
#pragma unroll
        for (int j = 0; j < 4; ++j) {
            int r = m * 16 + ((lane >> 4) << 2) + j;
            float v0 = fmaxf((acc[m][0][j] - mu[m][j]) * rs[m][j] * g0 + b0, 0.f);
            float v1 = fmaxf((acc[m][1][j] - mu[m][j]) * rs[m][j] * g1 + b1, 0.f);
            unsigned int p0 = f2bf(v0), p1 = f2bf(v1);
            unsigned int o0 = (unsigned int)__shfl_xor((int)p0, 1);
            unsigned int o1 = (unsigned int)__shfl_xor((int)p1, 1);
            if (!(lane & 1)) {
                int cb = c0 * 2;
                int byte0 = (r * 256 + cb) ^ ((r & 7) << 4);
                int byte1 = (r * 256 + cb + 32) ^ ((r & 7) << 4);
                *(unsigned int*)((char*)dst + byte0) = (p0 & 0xffffu) | (o0 << 16);
                *(unsigned int*)((char*)dst + byte1) = (p1 & 0xffffu) | (o1 << 16);
            }
        }
    __syncthreads();
}

// Pack raw fragments (no GN) as bf16 pairs into a row-major global [N,128] array.
__device__ inline void frag_pack_global(const f32x4 (&acc)[2][2],
                                        unsigned short* __restrict__ dst,
                                        int n0, int N, int t)
{
    const int lane = t & 63, wave = t >> 6;
    const int c0 = wave * 32 + (lane & 15);
#pragma unroll
    for (int m = 0; m < 2; ++m)
#pragma unroll
        for (int j = 0; j < 4; ++j) {
            int r = m * 16 + ((lane >> 4) << 2) + j;
            int ng = n0 + r;
            unsigned int p0 = f2bf(acc[m][0][j]);
            unsigned int p1 = f2bf(acc[m][1][j]);
            unsigned int o0 = (unsigned int)__shfl_xor((int)p0, 1);
            unsigned int o1 = (unsigned int)__shfl_xor((int)p1, 1);
            if (!(lane & 1) && ng < N) {
                unsigned int* rowp = (unsigned int*)(dst + (size_t)ng * NCH);
                rowp[c0 >> 1]        = (p0 & 0xffffu) | (o0 << 16);
                rowp[(c0 + 16) >> 1] = (p1 & 0xffffu) | (o1 << 16);
            }
        }
}

// ---------------------------------------------------------------------------
// node_prep: per 32 nodes —
//   outbuf = agts @ Wa^T (f32)
//   q      = relu(GN(agts @ Wq^T))            (bf16, LDS only)
//   pq     = q @ Wc1q^T                       (bf16, global)
//   px     = ctx @ Wc1x^T                     (bf16, global)
// ---------------------------------------------------------------------------
__global__ __launch_bounds__(256) void node_prep_kernel(
    const float* __restrict__ agts, const float* __restrict__ ctx,
    const unsigned short* __restrict__ wbf,
    const float* __restrict__ g_q, const float* __restrict__ bt_q,
    float* __restrict__ outbuf,
    unsigned short* __restrict__ pq, unsigned short* __restrict__ px, int N)
{
    const int t = threadIdx.x;
    const int lane = t & 63, wave = t >> 6;
    const int n0 = blockIdx.x * NB;

    __shared__ unsigned short bfQ[NB * NCH];
    __shared__ __align__(16) float red_s[NB][4];
    __shared__ __align__(16) float red_q[NB][4];

    const unsigned short* Wq   = wbf + 16384;
    const unsigned short* Wc1q = wbf + 49152;
    const unsigned short* Wc1x = wbf + 65536;
    const unsigned short* Wa   = wbf + 98304;

    int r0 = n0 + (lane & 15);      if (r0 >= N) r0 = N - 1;
    int r1 = n0 + 16 + (lane & 15); if (r1 >= N) r1 = N - 1;

    const f32x4 z = { 0.f, 0.f, 0.f, 0.f };
    f32x4 accO[2][2] = { { z, z }, { z, z } };
    f32x4 accQ[2][2] = { { z, z }, { z, z } };
#pragma unroll
    for (int k = 0; k < 4; ++k) {
        const int koff = k * 32 + (lane >> 4) * 8;
        bf16x8 a[2], bo[2], bq[2];
        a[0] = load_row8<false>(agts, r0, koff);
        a[1] = load_row8<false>(agts, r1, koff);
#pragma unroll
        for (int n = 0; n < 2; ++n) {
            int wr = wave * 32 + n * 16 + (lane & 15);
            bo[n] = *(const bf16x8*)(Wa + (size_t)wr * NCH + koff);
            bq[n] = *(const bf16x8*)(Wq + (size_t)wr * NCH + koff);
        }
#pragma unroll
        for (int m = 0; m < 2; ++m)
#pragma unroll
            for (int n = 0; n < 2; ++n) {
                accO[m][n] = __builtin_amdgcn_mfma_f32_16x16x32_bf16(a[m], bo[n], accO[m][n], 0, 0, 0);
                accQ[m][n] = __builtin_amdgcn_mfma_f32_16x16x32_bf16(a[m], bq[n], accQ[m][n], 0, 0, 0);
            }
    }
    // f32 store of the Wa product
#pragma unroll
    for (int m = 0; m < 2; ++m)
#pragma unroll
        for (int n = 0; n < 2; ++n)
#pragma unroll
            for (int j = 0; j < 4; ++j) {
                int r = m * 16 + ((lane >> 4) << 2) + j;
                int ng = n0 + r;
                if (ng < N)
                    outbuf[(size_t)ng * NCH + wave * 32 + n * 16 + (lane & 15)] = accO[m][n][j];
            }
    // GN+relu q -> bfQ (swizzled LDS)
    float mu[2][4], rs[2][4];
    gn_frag_stats(accQ, red_s, red_q, t, mu, rs);
    gn_pack_store(accQ, mu, rs, g_q, bt_q, bfQ, t);

    // pq = q @ Wc1q^T ; px = ctx @ Wc1x^T (shared loop)
    f32x4 accPq[2][2] = { { z, z }, { z, z } };
    f32x4 accPx[2][2] = { { z, z }, { z, z } };
#pragma unroll
    for (int k = 0; k < 4; ++k) {
        const int koff = k * 32 + (lane >> 4) * 8;
        bf16x8 aq[2], ax[2], bq2[2], bx[2];
#pragma unroll
        for (int m = 0; m < 2; ++m) {
            int r = m * 16 + (lane & 15);
            int byte = (r * 256 + koff * 2) ^ ((r & 7) << 4);
            aq[m] = *(const bf16x8*)((const char*)bfQ + byte);
        }
        ax[0] = load_row8<false>(ctx, r0, koff);
        ax[1] = load_row8<false>(ctx, r1, koff);
#pragma unroll
        for (int n = 0; n < 2; ++n) {
            int wr = wave * 32 + n * 16 + (lane & 15);
            bq2[n] = *(const bf16x8*)(Wc1q + (size_t)wr * NCH + koff);
            bx[n]  = *(const bf16x8*)(Wc1x + (size_t)wr * NCH + koff);
        }
#pragma unroll
        for (int m = 0; m < 2; ++m)
#pragma unroll
            for (int n = 0; n < 2; ++n) {
                accPq[m][n] = __builtin_amdgcn_mfma_f32_16x16x32_bf16(aq[m], bq2[n], accPq[m][n], 0, 0, 0);
                accPx[m][n] = __builtin_amdgcn_mfma_f32_16x16x32_bf16(ax[m], bx[n], accPx[m][n], 0, 0, 0);
            }
    }
    frag_pack_global(accPq, pq, n0, N, t);
    frag_pack_global(accPx, px, n0, N, t);
}

// ---------------------------------------------------------------------------
// Edge pipeline (big path): d1 -> d2(GN) -> c1 = Wc1d@d2 + pq[hi] + px[wi]
//   (GN) -> c2 -> scatter.  One bf16 LDS tile + one f32 sum tile.
// ---------------------------------------------------------------------------
__global__ __launch_bounds__(256) void edge_kernel_pre(
    const unsigned short* __restrict__ pq, const unsigned short* __restrict__ px,
    const float* __restrict__ agt_ctrs, const float* __restrict__ ctx_ctrs,
    const int* __restrict__ hi, const int* __restrict__ wi,
    const float* __restrict__ w_d1, const float* __restrict__ b_d1,
    const float* __restrict__ g_d2, const float* __restrict__ bt_d2,
    const float* __restrict__ g_c1, const float* __restrict__ bt_c1,
    const unsigned short* __restrict__ wbf,
    float* __restrict__ outbuf, int E)
{
    const int t = threadIdx.x;
    const int lane = t & 63;
    const int wave = t >> 6;
    const int e0 = blockIdx.x * EB;

    __shared__ unsigned short bfD[EB * NCH];
    __shared__ float S[EB][NCH + 4];
    __shared__ __align__(16) float red_s[EB][4];
    __shared__ __align__(16) float red_q[EB][4];
    __shared__ int   sh_h[EB], sh_w[EB];
    __shared__ float sh_dx[EB], sh_dy[EB];

    const unsigned short* Wd2  = wbf;
    const unsigned short* Wc1d = wbf + 32768;
    const unsigned short* Wc2  = wbf + 81920;

    if (t < EB) {
        int e = e0 + t; if (e >= E) e = E - 1;
        int h = hi[e], w = wi[e];
        sh_h[t] = h; sh_w[t] = w;
        sh_dx[t] = agt_ctrs[2 * h]     - ctx_ctrs[2 * w];
        sh_dy[t] = agt_ctrs[2 * h + 1] - ctx_ctrs[2 * w + 1];
    }
    __syncthreads();

    // ---- stage S = pq[hi] + px[wi] (f32), coalesced 8-elem chunks ----
    {
        const int r  = t >> 3;
        const int cc = t & 7;
        const int h = sh_h[r], w = sh_w[r];
#pragma unroll
        for (int half = 0; half < 2; ++half) {
            int c8 = (cc + half * 8) * 8;
            bf16x8 aq = load_row8<true>(pq, h, c8);
            bf16x8 ax = load_row8<true>(px, w, c8);
#pragma unroll
            for (int i = 0; i < 8; ++i)
                S[r][c8 + i] = bf2f((unsigned short)aq[i]) + bf2f((unsigned short)ax[i]);
        }
    }
    // ---- d1 = relu(w_d1 . [dx,dy] + b_d1) -> bfD ----
    {
        const int c = t & 127, rh = t >> 7;
        const float wa = w_d1[2 * c], wb = w_d1[2 * c + 1], bb = b_d1[c];
#pragma unroll
        for (int i = 0; i < 16; ++i) {
            int r = rh * 16 + i;
            float v = fmaxf(fmaf(wa, sh_dx[r], fmaf(wb, sh_dy[r], bb)), 0.f);
            unsigned int pv = f2bf(v);
            unsigned int ov = (unsigned int)__shfl_xor((int)pv, 1);
            if (!(c & 1)) {
                int byte = (r * 256 + c * 2) ^ ((r & 7) << 4);
                *(unsigned int*)((char*)bfD + byte) = (pv & 0xffffu) | (ov << 16);
            }
        }
    }
    __syncthreads();

    const f32x4 z = { 0.f, 0.f, 0.f, 0.f };
    f32x4 acc[2][2];
    float mu[2][4], rs[2][4];

    // ---- d2 = relu(GN(d1 @ Wd2^T)) -> bfD ----
    acc[0][0] = z; acc[0][1] = z; acc[1][0] = z; acc[1][1] = z;
    gemm_k128_lds(bfD, Wd2, lane, wave, acc);
    gn_frag_stats(acc, red_s, red_q, t, mu, rs);
    gn_pack_store(acc, mu, rs, g_d2, bt_d2, bfD, t);

    // ---- c1 = relu(GN(d2 @ Wc1d^T + S)) -> bfD ----
    acc[0][0] = z; acc[0][1] = z; acc[1][0] = z; acc[1][1] = z;
    gemm_k128_lds(bfD, Wc1d, lane, wave, acc);
    {
        const int c0 = wave * 32 + (lane & 15);
#pragma unroll
        for (int m = 0; m < 2; ++m)
#pragma unroll
            for (int j = 0; j < 4; ++j) {
                int r = m * 16 + ((lane >> 4) << 2) + j;
                acc[m][0][j] += S[r][c0];
                acc[m][1][j] += S[r][c0 + 16];
            }
    }
    gn_frag_stats(acc, red_s, red_q, t, mu, rs);
    gn_pack_store(acc, mu, rs, g_c1, bt_c1, bfD, t);

    // ---- e = c1 @ Wc2^T ; scatter-add to outbuf[hi] ----
    acc[0][0] = z; acc[0][1] = z; acc[1][0] = z; acc[1][1] = z;
    gemm_k128_lds(bfD, Wc2, lane, wave, acc);
#pragma unroll
    for (int m = 0; m < 2; ++m)
#pragma unroll
        for (int n = 0; n < 2; ++n)
#pragma unroll
            for (int j = 0; j < 4; ++j) {
                int r = m * 16 + ((lane >> 4) << 2) + j;
                if (e0 + r < E)
                    atomicAdd(&outbuf[(size_t)sh_h[r] * NCH + wave * 32 + n * 16 + (lane & 15)],
                              acc[m][n][j]);
            }
}

// ---------------------------------------------------------------------------
// Fallback edge kernel (no workspace): full in-kernel pipeline from f32 inputs.
// ---------------------------------------------------------------------------
__global__ __launch_bounds__(256) void edge_kernel_fb(
    const float* __restrict__ agts, const float* __restrict__ ctx,
    const float* __restrict__ agt_ctrs, const float* __restrict__ ctx_ctrs,
    const int* __restrict__ hi, const int* __restrict__ wi,
    const float* __restrict__ w_d1, const float* __restrict__ b_d1,
    const float* __restrict__ g_d2, const float* __restrict__ bt_d2,
    const float* __restrict__ g_q, const float* __restrict__ bt_q,
    const float* __restrict__ g_c1, const float* __restrict__ bt_c1,
    const unsigned short* __restrict__ wbf,
    float* __restrict__ outbuf, int E)
{
    const int t = threadIdx.x;
    const int lane = t & 63;
    const int wave = t >> 6;
    const int e0 = blockIdx.x * EB;

    __shared__ unsigned short bfQ[EB * NCH];
    __shared__ unsigned short bfD[EB * NCH];
    __shared__ unsigned short bfX[EB * NCH];
    __shared__ __align__(16) float red_s[EB][4];
    __shared__ __align__(16) float red_q[EB][4];
    __shared__ int   sh_h[EB], sh_w[EB];
    __shared__ float sh_dx[EB], sh_dy[EB];

    const unsigned short* Wd2 = wbf;
    const unsigned short* Wq  = wbf + 16384;
    const unsigned short* Wc1d = wbf + 32768;
    const unsigned short* Wc1q = wbf + 49152;
    const unsigned short* Wc1x = wbf + 65536;
    const unsigned short* Wc2 = wbf + 81920;

    if (t < EB) {
        int e = e0 + t; if (e >= E) e = E - 1;
        int h = hi[e], w = wi[e];
        sh_h[t] = h; sh_w[t] = w;
        sh_dx[t] = agt_ctrs[2 * h]     - ctx_ctrs[2 * w];
        sh_dy[t] = agt_ctrs[2 * h + 1] - ctx_ctrs[2 * w + 1];
    }
    __syncthreads();
    {
        const int r  = t >> 3;
        const int cc = t & 7;
        const int h = sh_h[r], w = sh_w[r];
#pragma unroll
        for (int half = 0; half < 2; ++half) {
            int c = cc + half * 8;
            bf16x8 qv = load_row8<false>(agts, h, c * 8);
            bf16x8 xv = load_row8<false>(ctx, w, c * 8);
            int byte = (r * 256 + c * 16) ^ ((r & 7) << 4);
            *(bf16x8*)((char*)bfQ + byte) = qv;
            *(bf16x8*)((char*)bfX + byte) = xv;
        }
    }
    {
        const int c = t & 127, rh = t >> 7;
        const float wa = w_d1[2 * c], wb = w_d1[2 * c + 1], bb = b_d1[c];
#pragma unroll
        for (int i = 0; i < 16; ++i) {
            int r = rh * 16 + i;
            float v = fmaxf(fmaf(wa, sh_dx[r], fmaf(wb, sh_dy[r], bb)), 0.f);
            unsigned int pv = f2bf(v);
            unsigned int ov = (unsigned int)__shfl_xor((int)pv, 1);
            if (!(c & 1)) {
                int byte = (r * 256 + c * 2) ^ ((r & 7) << 4);
                *(unsigned int*)((char*)bfD + byte) = (pv & 0xffffu) | (ov << 16);
            }
        }
    }
    __syncthreads();

    const f32x4 z = { 0.f, 0.f, 0.f, 0.f };
    f32x4 acc[2][2];
    float mu[2][4], rs[2][4];

    acc[0][0] = z; acc[0][1] = z; acc[1][0] = z; acc[1][1] = z;
    gemm_k128_lds(bfD, Wd2, lane, wave, acc);
    gn_frag_stats(acc, red_s, red_q, t, mu, rs);
    gn_pack_store(acc, mu, rs, g_d2, bt_d2, bfD, t);

    acc[0][0] = z; acc[0][1] = z; acc[1][0] = z; acc[1][1] = z;
    gemm_k128_lds(bfQ, Wq, lane, wave, acc);
    gn_frag_stats(acc, red_s, red_q, t, mu, rs);
    gn_pack_store(acc, mu, rs, g_q, bt_q, bfQ, t);

    acc[0][0] = z; acc[0][1] = z; acc[1][0] = z; acc[1][1] = z;
    gemm_k128_lds(bfD, Wc1d, lane, wave, acc);
    gemm_k128_lds(bfQ, Wc1q, lane, wave, acc);
    gemm_k128_lds(bfX, Wc1x, lane, wave, acc);
    gn_frag_stats(acc, red_s, red_q, t, mu, rs);
    gn_pack_store(acc, mu, rs, g_c1, bt_c1, bfD, t);

    acc[0][0] = z; acc[0][1] = z; acc[1][0] = z; acc[1][1] = z;
    gemm_k128_lds(bfD, Wc2, lane, wave, acc);
#pragma unroll
    for (int m = 0; m < 2; ++m)
#pragma unroll
        for (int n = 0; n < 2; ++n)
#pragma unroll
            for (int j = 0; j < 4; ++j) {
                int r = m * 16 + ((lane >> 4) << 2) + j;
                if (e0 + r < E)
                    atomicAdd(&outbuf[(size_t)sh_h[r] * NCH + wave * 32 + n * 16 + (lane & 15)],
                              acc[m][n][j]);
            }
}

// ---------------------------------------------------------------------------
// node_init (fallback only): out = agts @ w_a^T via MFMA.
// ---------------------------------------------------------------------------
__global__ __launch_bounds__(256) void node_init_kernel(
    const float* __restrict__ agts, const unsigned short* __restrict__ wa_bf,
    float* __restrict__ outbuf, int N)
{
    const int t = threadIdx.x;
    const int lane = t & 63, wave = t >> 6;
    const int n0 = blockIdx.x * NB;

    int r0 = n0 + (lane & 15);      if (r0 >= N) r0 = N - 1;
    int r1 = n0 + 16 + (lane & 15); if (r1 >= N) r1 = N - 1;

    const f32x4 z = { 0.f, 0.f, 0.f, 0.f };
    f32x4 acc[2][2] = { { z, z }, { z, z } };
#pragma unroll
    for (int k = 0; k < 4; ++k) {
        const int koff = k * 32 + (lane >> 4) * 8;
        bf16x8 a[2], b[2];
        a[0] = load_row8<false>(agts, r0, koff);
        a[1] = load_row8<false>(agts, r1, koff);
#pragma unroll
        for (int n = 0; n < 2; ++n) {
            int wr = wave * 32 + n * 16 + (lane & 15);
            b[n] = *(const bf16x8*)(wa_bf + (size_t)wr * NCH + koff);
        }
#pragma unroll
        for (int m = 0; m < 2; ++m)
#pragma unroll
            for (int n = 0; n < 2; ++n)
                acc[m][n] = __builtin_amdgcn_mfma_f32_16x16x32_bf16(a[m], b[n], acc[m][n], 0, 0, 0);
    }
#pragma unroll
    for (int m = 0; m < 2; ++m)
#pragma unroll
        for (int n = 0; n < 2; ++n)
#pragma unroll
            for (int j = 0; j < 4; ++j) {
                int r = m * 16 + ((lane >> 4) << 2) + j;
                int ng = n0 + r;
                if (ng < N)
                    outbuf[(size_t)ng * NCH + wave * 32 + n * 16 + (lane & 15)] = acc[m][n][j];
            }
}

// ---------------------------------------------------------------------------
// node_post: relu(GN(out)) -> GN(out @ w_l^T) -> relu(+ res), in place, MFMA.
// ---------------------------------------------------------------------------
__global__ __launch_bounds__(256) void node_post_kernel(
    float* __restrict__ outbuf, const float* __restrict__ agts,
    const float* __restrict__ g_n, const float* __restrict__ bt_n,
    const unsigned short* __restrict__ wl_bf,
    const float* __restrict__ g_l, const float* __restrict__ bt_l, int N)
{
    const int t = threadIdx.x;
    const int lane = t & 63, wave = t >> 6;
    const int n0 = blockIdx.x * NB;

    __shared__ unsigned short bfP[NB * NCH];
    __shared__ __align__(16) float red_s[NB][4];
    __shared__ __align__(16) float red_q[NB][4];

    const int c = t & 127, rh = t >> 7;
    float v[16];
#pragma unroll
    for (int i = 0; i < 16; ++i) {
        int n = n0 + rh * 16 + i; if (n >= N) n = N - 1;
        v[i] = outbuf[(size_t)n * NCH + c];
    }
#pragma unroll
    for (int i = 0; i < 16; ++i) {
        float s = v[i], q = v[i] * v[i];
        for (int off = 32; off > 0; off >>= 1) {
            s += __shfl_down(s, off);
            q += __shfl_down(q, off);
        }
        if (lane == 0) { red_s[rh * 16 + i][wave & 1] = s; red_q[rh * 16 + i][wave & 1] = q; }
    }
    __syncthreads();
    {
        const float g = g_n[c], b = bt_n[c];
#pragma unroll
        for (int i = 0; i < 16; ++i) {
            int r = rh * 16 + i;
            float s = red_s[r][0] + red_s[r][1];
            float q = red_q[r][0] + red_q[r][1];
            float m_  = s * (1.f / NCH);
            float var = q * (1.f / NCH) - m_ * m_;
            float rrs = rsqrtf(var + 1e-5f);
            float val = fmaxf((v[i] - m_) * rrs * g + b, 0.f);
            unsigned int pv = f2bf(val);
            unsigned int ov = (unsigned int)__shfl_xor((int)pv, 1);
            if (!(c & 1)) {
                int byte = (r * 256 + c * 2) ^ ((r & 7) << 4);
                *(unsigned int*)((char*)bfP + byte) = (pv & 0xffffu) | (ov << 16);
            }
        }
    }
    __syncthreads();

    const f32x4 z = { 0.f, 0.f, 0.f, 0.f };
    f32x4 acc[2][2] = { { z, z }, { z, z } };
    gemm_k128_lds(bfP, wl_bf, lane, wave, acc);

    float mu[2][4], rs[2][4];
    gn_frag_stats(acc, red_s, red_q, t, mu, rs);
    const int c0 = wave * 32 + (lane & 15);
    const float g0 = g_l[c0],      b0 = bt_l[c0];
    const float g1 = g_l[c0 + 16], b1 = bt_l[c0 + 16];
#pragma unroll
    for (int m = 0; m < 2; ++m)
#pragma unroll
        for (int j = 0; j < 4; ++j) {
            int r = m * 16 + ((lane >> 4) << 2) + j;
            int ng = n0 + r;
            if (ng < N) {
                float v0 = (acc[m][0][j] - mu[m][j]) * rs[m][j] * g0 + b0;
                float v1 = (acc[m][1][j] - mu[m][j]) * rs[m][j] * g1 + b1;
                v0 = fmaxf(v0 + agts[(size_t)ng * NCH + c0], 0.f);
                v1 = fmaxf(v1 + agts[(size_t)ng * NCH + c0 + 16], 0.f);
                outbuf[(size_t)ng * NCH + c0]      = v0;
                outbuf[(size_t)ng * NCH + c0 + 16] = v1;
            }
        }
}

// ---------------------------------------------------------------------------
extern "C" void kernel_launch(void* const* d_in, const int* in_sizes, int n_in,
                              void* d_out, int out_size, void* d_ws, size_t ws_size,
                              hipStream_t stream) {
    const float* agts     = (const float*)d_in[0];
    const float* ctx      = (const float*)d_in[1];
    const float* agt_ctrs = (const float*)d_in[2];
    const float* ctx_ctrs = (const float*)d_in[3];
    const int*   hi       = (const int*)d_in[4];
    const int*   wi       = (const int*)d_in[5];
    const float* w_d1     = (const float*)d_in[6];
    const float* b_d1     = (const float*)d_in[7];
    const float* w_d2     = (const float*)d_in[8];
    const float* g_d2     = (const float*)d_in[9];
    const float* bt_d2    = (const float*)d_in[10];
    const float* w_q      = (const float*)d_in[11];
    const float* g_q      = (const float*)d_in[12];
    const float* bt_q     = (const float*)d_in[13];
    const float* w_c1     = (const float*)d_in[14];
    const float* g_c1     = (const float*)d_in[15];
    const float* bt_c1    = (const float*)d_in[16];
    const float* w_c2     = (const float*)d_in[17];
    const float* w_a      = (const float*)d_in[18];
    const float* g_n      = (const float*)d_in[19];
    const float* bt_n     = (const float*)d_in[20];
    const float* w_l      = (const float*)d_in[21];
    const float* g_l      = (const float*)d_in[22];
    const float* bt_l     = (const float*)d_in[23];

    const int N = in_sizes[0] / NCH;
    const int E = in_sizes[4];

    float* outbuf = (float*)d_out;                 // [N,128] f32 accumulator

    unsigned short* wbf = (unsigned short*)d_ws;   // 131072 bf16 weights
    unsigned short* pq  = wbf + 131072;            // Wc1q @ q   per node (bf16)
    unsigned short* px  = pq + (size_t)N * NCH;    // Wc1x @ ctx per node (bf16)
    const size_t need = 262144ull + (size_t)N * NCH * 4ull;  // bytes
    const bool big = (d_ws != nullptr) && (ws_size >= need);

    const int nb_nodes = (N + NB - 1) / NB;
    const int nb_edges = (E + EB - 1) / EB;

    convert_weights_kernel<<<512, 256, 0, stream>>>(w_d2, w_q, w_c1, w_c2, w_a, w_l, wbf);

    if (big) {
        node_prep_kernel<<<nb_nodes, 256, 0, stream>>>(
            agts, ctx, wbf, g_q, bt_q, outbuf, pq, px, N);
        edge_kernel_pre<<<nb_edges, 256, 0, stream>>>(
            pq, px, agt_ctrs, ctx_ctrs, hi, wi,
            w_d1, b_d1, g_d2, bt_d2, g_c1, bt_c1,
            wbf, outbuf, E);
    } else {
        node_init_kernel<<<nb_nodes, 256, 0, stream>>>(agts, wbf + 98304, outbuf, N);
        edge_kernel_fb<<<nb_edges, 256, 0, stream>>>(
            agts, ctx, agt_ctrs, ctx_ctrs, hi, wi,
            w_d1, b_d1, g_d2, bt_d2, g_q, bt_q, g_c1, bt_c1,
            wbf, outbuf, E);
    }
    node_post_kernel<<<nb_nodes, 256, 0, stream>>>(
        outbuf, agts, g_n, bt_n, wbf + 114688, g_l, bt_l, N);
}